// Round 19
// baseline (400.512 us; speedup 1.0000x reference)
//
#include <hip/hip_runtime.h>
#include <math.h>

// Problem constants (from reference)
constexpr int N_NODES = 50000;
constexpr int N_EDGES = 800000;
constexpr int TOT_E   = N_EDGES + N_NODES;   // + self loops
constexpr int MAXD    = 256;                 // LDS logit-cache capacity per wave

// padded atomic counters: one int per 128B line (stride 32 ints)
constexpr int PADSH = 5;

// prep_k section sizes
constexpr int PREP_CVT  = (N_NODES * 128 / 4 + 255) / 256;   // 6250
constexpr int PREP_W0B  = 128;                               // W0 -> bf16 copy
constexpr int PREP_DEG  = (TOT_E + 255) / 256;               // 3321
constexpr int PREP_SKIN = (N_NODES + 15) / 16;               // 3125 (as0/ad0 dots)
constexpr int PREP_C    = 1;                                 // c2 = Wl^T b1 + bl
constexpr int PREP_BLKS = PREP_CVT + PREP_W0B + PREP_DEG + PREP_SKIN + PREP_C;

typedef __attribute__((ext_vector_type(8))) short bf16x8;
typedef __attribute__((ext_vector_type(4))) float f32x4;
typedef __attribute__((ext_vector_type(2))) float f32x2;

// ---- bf16 helpers (manual RNE, deterministic) ----
__device__ __forceinline__ unsigned short f2bf(float f) {
    unsigned int u = __float_as_uint(f);
    unsigned int r = (u + 0x7fffu + ((u >> 16) & 1u)) >> 16;
    return (unsigned short)r;
}
__device__ __forceinline__ unsigned int f2bf_pack(float lo, float hi) {
    return (unsigned int)f2bf(lo) | ((unsigned int)f2bf(hi) << 16);
}
__device__ __forceinline__ float bf2f_lo(unsigned int packed) {
    return __uint_as_float(packed << 16);
}
__device__ __forceinline__ float bf2f_hi(unsigned int packed) {
    return __uint_as_float(packed & 0xffff0000u);
}

__device__ __forceinline__ float lrelu(float x) { return x > 0.f ? x : 0.2f * x; }

// ---------------- kernel 1: zero padded deg counters + total + c2,
// block 0 additionally precomputes pushdown vectors w0buf/pv ----

__global__ __launch_bounds__(256) void zero_pre_k(uint4* __restrict__ degp4,
        int* __restrict__ total, float* __restrict__ c2,
        const float* __restrict__ W0, const float* __restrict__ att_src0,
        const float* __restrict__ att_dst0,
        const float* __restrict__ W1, const float* __restrict__ att_src1,
        const float* __restrict__ att_dst1, const float* __restrict__ Wl,
        float* __restrict__ w0buf, float* __restrict__ pv) {
    int i = blockIdx.x * blockDim.x + threadIdx.x;
    if (i < N_NODES * 32 / 4) degp4[i] = make_uint4(0, 0, 0, 0);
    if (blockIdx.x == 0) {
        if (threadIdx.x == 0) { *total = 0; c2[0] = 0.f; c2[1] = 0.f; }
        int k = threadIdx.x;                  // 0..255
        // pv[k][0..7]: (vs1_h0, vs1_h1, vd1_h0, vd1_h1, u00, u01, u10, u11)
        float v0 = 0, v1 = 0, v2 = 0, v3 = 0, v4 = 0, v5 = 0, v6 = 0, v7 = 0;
        const float* wr = W1 + (size_t)k * 256;
        for (int c = 0; c < 128; ++c) {
            float wv = wr[c];
            v0 = fmaf(wv, att_src1[c], v0);
            v2 = fmaf(wv, att_dst1[c], v2);
            v4 = fmaf(wv, Wl[c * 2 + 0], v4);
            v5 = fmaf(wv, Wl[c * 2 + 1], v5);
        }
        for (int c = 128; c < 256; ++c) {
            float wv = wr[c];
            v1 = fmaf(wv, att_src1[c], v1);
            v3 = fmaf(wv, att_dst1[c], v3);
            v6 = fmaf(wv, Wl[c * 2 + 0], v6);
            v7 = fmaf(wv, Wl[c * 2 + 1], v7);
        }
        float* p = pv + (size_t)k * 8;
        p[0] = v0; p[1] = v1; p[2] = v2; p[3] = v3;
        p[4] = v4; p[5] = v5; p[6] = v6; p[7] = v7;
        if (k < 128) {
            // w0buf[k][0..3] = (ws0_h0, ws0_h1, wd0_h0, wd0_h1)
            float w0v = 0, w1v = 0, w2v = 0, w3v = 0;
            const float* wr0 = W0 + (size_t)k * 256;
            for (int c = 0; c < 128; ++c) {
                float wv = wr0[c];
                w0v = fmaf(wv, att_src0[c], w0v);
                w2v = fmaf(wv, att_dst0[c], w2v);
            }
            for (int c = 128; c < 256; ++c) {
                float wv = wr0[c];
                w1v = fmaf(wv, att_src0[c], w1v);
                w3v = fmaf(wv, att_dst0[c], w3v);
            }
            float* q = w0buf + (size_t)k * 4;
            q[0] = w0v; q[1] = w1v; q[2] = w2v; q[3] = w3v;
        }
    }
}

// ---------------- kernel 2: fused prep ----------------
// cvt x->xb | W0 -> bf16 | degree count | skinny as0/ad0 | c2

__global__ __launch_bounds__(256) void prep_k(const float* __restrict__ x,
        unsigned short* __restrict__ xb, const float* __restrict__ W0,
        unsigned short* __restrict__ W0b, const int* __restrict__ ei,
        int* __restrict__ degp,
        const float* __restrict__ w0buf, float* __restrict__ a_s,
        float* __restrict__ a_d, const float* __restrict__ Wl,
        const float* __restrict__ b1, const float* __restrict__ bl,
        float* __restrict__ c2) {
    int b = blockIdx.x;
    if (b < PREP_CVT) {                       // x -> bf16 (float4 quads)
        int i = b * 256 + threadIdx.x;
        if (i < N_NODES * 128 / 4) {
            float4 v = *reinterpret_cast<const float4*>(x + (size_t)i * 4);
            ushort4 o;
            o.x = f2bf(v.x); o.y = f2bf(v.y); o.z = f2bf(v.z); o.w = f2bf(v.w);
            *reinterpret_cast<ushort4*>(xb + (size_t)i * 4) = o;
        }
        return;
    }
    b -= PREP_CVT;
    if (b < PREP_W0B) {                       // W0b[k][c] = bf16(W0[k][c])
        int idx = b * 256 + threadIdx.x;
        W0b[idx] = f2bf(W0[idx]);
        return;
    }
    b -= PREP_W0B;
    if (b < PREP_DEG) {                       // degree count (padded counters)
        int e = b * 256 + threadIdx.x;
        if (e < TOT_E) {
            int dst = (e < N_EDGES) ? ei[N_EDGES + e] : (e - N_EDGES);
            atomicAdd(&degp[dst << PADSH], 1);
        }
        return;
    }
    b -= PREP_DEG;
    if (b < PREP_SKIN) {                      // as0/ad0 = x . w0buf  (16 nodes/block)
        int lane = threadIdx.x & 63;
        int sub = lane >> 4;
        int lq = lane & 15;
        int node = b * 16 + (threadIdx.x >> 6) * 4 + sub;
        if (node < N_NODES) {
            const float* xr = x + (size_t)node * 128 + lq * 8;
            const float4* wv = reinterpret_cast<const float4*>(w0buf) + lq * 8;
            float s0 = 0, s1 = 0, d0 = 0, d1 = 0;
#pragma unroll
            for (int t = 0; t < 8; ++t) {
                float xv = xr[t];
                float4 w = wv[t];
                s0 = fmaf(xv, w.x, s0);
                s1 = fmaf(xv, w.y, s1);
                d0 = fmaf(xv, w.z, d0);
                d1 = fmaf(xv, w.w, d1);
            }
#pragma unroll
            for (int off = 1; off < 16; off <<= 1) {
                s0 += __shfl_xor(s0, off);
                s1 += __shfl_xor(s1, off);
                d0 += __shfl_xor(d0, off);
                d1 += __shfl_xor(d1, off);
            }
            if (lq == 0) {
                *reinterpret_cast<float2*>(a_s + node * 2) = make_float2(s0, s1);
                *reinterpret_cast<float2*>(a_d + node * 2) = make_float2(d0, d1);
            }
        }
        return;
    }
    {                                         // c2 = Wl^T b1 + bl (one block)
        int k = threadIdx.x;
        int lane = k & 63;
        float bv = b1[k];
        float p0 = bv * Wl[k * 2 + 0];
        float p1 = bv * Wl[k * 2 + 1];
        if (k == 0) { p0 += bl[0]; p1 += bl[1]; }
#pragma unroll
        for (int off = 32; off; off >>= 1) {
            p0 += __shfl_xor(p0, off);
            p1 += __shfl_xor(p1, off);
        }
        if (lane == 0) {
            atomicAdd(&c2[0], p0);
            atomicAdd(&c2[1], p1);
        }
    }
}

// ---------------- CSR build ----------------

__global__ void offsets_k(const int* __restrict__ degp, int* __restrict__ start,
                          int* __restrict__ deg, int* __restrict__ cursorp,
                          int* __restrict__ total) {
    int lane = threadIdx.x & 63;
    int node = blockIdx.x * blockDim.x + threadIdx.x;
    int d = (node < N_NODES) ? degp[node << PADSH] : 0;
    int pre = d;
#pragma unroll
    for (int off = 1; off < 64; off <<= 1) {
        int v = __shfl_up(pre, off);
        if (lane >= off) pre += v;
    }
    int wtot = __shfl(pre, 63);
    int base = 0;
    if (lane == 63) base = atomicAdd(total, wtot);
    base = __shfl(base, 63);
    int my = base + pre - d;
    if (node < N_NODES) {
        start[node] = my;
        deg[node] = d;
        cursorp[node << PADSH] = my;
    }
}

__global__ void scatter_k(const int* __restrict__ ei, int* __restrict__ cursorp,
                          int* __restrict__ colv) {
    int e = blockIdx.x * blockDim.x + threadIdx.x;
    if (e >= TOT_E) return;
    int srcv, dstv;
    if (e < N_EDGES) { srcv = ei[e]; dstv = ei[N_EDGES + e]; }
    else             { srcv = dstv = e - N_EDGES; }
    int pos = atomicAdd(&cursorp[dstv << PADSH], 1);
    colv[pos] = srcv;
}

// ---------------- layer-0 aggregation over x + fused W0 matvec + tanh +
// projection dots -> asd1[n][8]. One wave per node; xagg parked in LDS;
// all 64 lanes share the 128-iter matvec (lane owns 4 output cols). ----

__global__ __launch_bounds__(256) void agg0x_k(const unsigned short* __restrict__ xb,
                      const float* __restrict__ a_s, const float* __restrict__ a_d,
                      const int* __restrict__ start, const int* __restrict__ deg,
                      const int* __restrict__ colv,
                      const unsigned short* __restrict__ W0b,  // [128][256] bf16
                      const float* __restrict__ b0,
                      const float* __restrict__ pv,            // [256][8] fp32
                      float* __restrict__ asd1) {
    __shared__ float lexp[4][MAXD][2];
    __shared__ float xsh[4][2][128];
    const int lane = threadIdx.x & 63;
    const int wslot = threadIdx.x >> 6;
    const int node = blockIdx.x * 4 + wslot;
    if (node >= N_NODES) return;
    const int beg = start[node];
    const int degv = deg[node];
    const float ad0 = a_d[node * 2], ad1 = a_d[node * 2 + 1];
    const int* __restrict__ col = colv + beg;

    if (degv <= MAXD) {
        // ---- pass A: gather a_s, exp (max-free), stash to LDS, sum ----
        float s0 = 0.f, s1 = 0.f;
        for (int j = lane; j < degv; j += 64) {
            int s = col[j];
            float2 av = *reinterpret_cast<const float2*>(a_s + s * 2);
            float e0 = __expf(lrelu(av.x + ad0));
            float e1 = __expf(lrelu(av.y + ad1));
            *reinterpret_cast<float2*>(&lexp[wslot][j][0]) = make_float2(e0, e1);
            s0 += e0;
            s1 += e1;
        }
#pragma unroll
        for (int off = 32; off; off >>= 1) {
            s0 += __shfl_xor(s0, off);
            s1 += __shfl_xor(s1, off);
        }
        const float inv0 = 1.f / (s0 + 1e-16f);
        const float inv1 = 1.f / (s1 + 1e-16f);

        // ---- pass B: 4 edges/iter; quarter q owns edge 4i+q; lane covers
        // 8 x-channels [lq*8, lq*8+8); dual (e0,e1)-weighted accumulate ----
        const int q = lane >> 4;
        const int lq = lane & 15;
        const unsigned short* __restrict__ xp = xb + lq * 8;
        f32x2 aA[4] = {};   // e0-weighted
        f32x2 aB[4] = {};   // e1-weighted
        const int full = degv >> 2;
        for (int i = 0; i < full; ++i) {
            const int j = 4 * i + q;
            const int s = col[j];
            float2 ee = *reinterpret_cast<float2*>(&lexp[wslot][j][0]);
            const uint4 hv = *reinterpret_cast<const uint4*>(xp + (size_t)s * 128);
            const f32x2 al0 = {ee.x, ee.x};
            const f32x2 al1 = {ee.y, ee.y};
            f32x2 p;
            p.x = bf2f_lo(hv.x); p.y = bf2f_hi(hv.x);
            aA[0] = __builtin_elementwise_fma(p, al0, aA[0]);
            aB[0] = __builtin_elementwise_fma(p, al1, aB[0]);
            p.x = bf2f_lo(hv.y); p.y = bf2f_hi(hv.y);
            aA[1] = __builtin_elementwise_fma(p, al0, aA[1]);
            aB[1] = __builtin_elementwise_fma(p, al1, aB[1]);
            p.x = bf2f_lo(hv.z); p.y = bf2f_hi(hv.z);
            aA[2] = __builtin_elementwise_fma(p, al0, aA[2]);
            aB[2] = __builtin_elementwise_fma(p, al1, aB[2]);
            p.x = bf2f_lo(hv.w); p.y = bf2f_hi(hv.w);
            aA[3] = __builtin_elementwise_fma(p, al0, aA[3]);
            aB[3] = __builtin_elementwise_fma(p, al1, aB[3]);
        }
        {   // tail (degv & 3 edges)
            const int j = full * 4 + q;
            if (j < degv) {
                const int s = col[j];
                float2 ee = *reinterpret_cast<float2*>(&lexp[wslot][j][0]);
                const uint4 hv = *reinterpret_cast<const uint4*>(xp + (size_t)s * 128);
                const f32x2 al0 = {ee.x, ee.x};
                const f32x2 al1 = {ee.y, ee.y};
                f32x2 p;
                p.x = bf2f_lo(hv.x); p.y = bf2f_hi(hv.x);
                aA[0] = __builtin_elementwise_fma(p, al0, aA[0]);
                aB[0] = __builtin_elementwise_fma(p, al1, aB[0]);
                p.x = bf2f_lo(hv.y); p.y = bf2f_hi(hv.y);
                aA[1] = __builtin_elementwise_fma(p, al0, aA[1]);
                aB[1] = __builtin_elementwise_fma(p, al1, aB[1]);
                p.x = bf2f_lo(hv.z); p.y = bf2f_hi(hv.z);
                aA[2] = __builtin_elementwise_fma(p, al0, aA[2]);
                aB[2] = __builtin_elementwise_fma(p, al1, aB[2]);
                p.x = bf2f_lo(hv.w); p.y = bf2f_hi(hv.w);
                aA[3] = __builtin_elementwise_fma(p, al0, aA[3]);
                aB[3] = __builtin_elementwise_fma(p, al1, aB[3]);
            }
        }
        float acc[16];
#pragma unroll
        for (int c = 0; c < 4; ++c) {
            acc[2 * c]     = aA[c].x;
            acc[2 * c + 1] = aA[c].y;
            acc[8 + 2 * c]     = aB[c].x;
            acc[8 + 2 * c + 1] = aB[c].y;
        }
#pragma unroll
        for (int c = 0; c < 16; ++c) {
            acc[c] += __shfl_xor(acc[c], 16);
            acc[c] += __shfl_xor(acc[c], 32);
        }
        if (lane < 16) {
#pragma unroll
            for (int c = 0; c < 8; ++c) {
                xsh[wslot][0][lq * 8 + c] = acc[c] * inv0;
                xsh[wslot][1][lq * 8 + c] = acc[8 + c] * inv1;
            }
        }
    } else {
        // ---- fallback: 3-pass max-subtracted; lane covers 2 x-channels ----
        const int end = beg + degv;
        float m0 = -INFINITY, m1 = -INFINITY;
        for (int e = beg + lane; e < end; e += 64) {
            int s = colv[e];
            m0 = fmaxf(m0, lrelu(a_s[s * 2] + ad0));
            m1 = fmaxf(m1, lrelu(a_s[s * 2 + 1] + ad1));
        }
#pragma unroll
        for (int off = 32; off; off >>= 1) {
            m0 = fmaxf(m0, __shfl_xor(m0, off));
            m1 = fmaxf(m1, __shfl_xor(m1, off));
        }
        float s0 = 0.f, s1 = 0.f;
        for (int e = beg + lane; e < end; e += 64) {
            int s = colv[e];
            s0 += __expf(lrelu(a_s[s * 2] + ad0) - m0);
            s1 += __expf(lrelu(a_s[s * 2 + 1] + ad1) - m1);
        }
#pragma unroll
        for (int off = 32; off; off >>= 1) {
            s0 += __shfl_xor(s0, off);
            s1 += __shfl_xor(s1, off);
        }
        float inv0 = 1.f / (s0 + 1e-16f);
        float inv1 = 1.f / (s1 + 1e-16f);
        const int cbase = lane * 2;
        float a00 = 0.f, a01 = 0.f, a10 = 0.f, a11 = 0.f;
        for (int e = beg; e < end; ++e) {
            int s = colv[e];
            float2 av = *reinterpret_cast<const float2*>(a_s + s * 2);
            float al0 = __expf(lrelu(av.x + ad0) - m0) * inv0;
            float al1 = __expf(lrelu(av.y + ad1) - m1) * inv1;
            unsigned int xv = *reinterpret_cast<const unsigned int*>(
                xb + (size_t)s * 128 + cbase);
            float x0 = bf2f_lo(xv), x1 = bf2f_hi(xv);
            a00 = fmaf(x0, al0, a00);
            a01 = fmaf(x1, al0, a01);
            a10 = fmaf(x0, al1, a10);
            a11 = fmaf(x1, al1, a11);
        }
        xsh[wslot][0][cbase]     = a00;
        xsh[wslot][0][cbase + 1] = a01;
        xsh[wslot][1][cbase]     = a10;
        xsh[wslot][1][cbase + 1] = a11;
    }

    // ---- fused epilogue: h = tanh(xagg_h @ W0 + b0); asd1 = h . pv ----
    // lane owns 4 cols c4..c4+3 of head = lane>>5. Same-wave LDS -> no barrier.
    const int head = lane >> 5;
    const int c4 = (lane & 31) * 4 + head * 128;
    const float* __restrict__ xv = &xsh[wslot][head][0];
    const unsigned short* __restrict__ wp = W0b + c4;
    float h0 = 0.f, h1 = 0.f, h2 = 0.f, h3 = 0.f;
#pragma unroll 8
    for (int k = 0; k < 128; ++k) {
        float xk = xv[k];
        uint2 wv4 = *reinterpret_cast<const uint2*>(wp + (size_t)k * 256);
        h0 = fmaf(bf2f_lo(wv4.x), xk, h0);
        h1 = fmaf(bf2f_hi(wv4.x), xk, h1);
        h2 = fmaf(bf2f_lo(wv4.y), xk, h2);
        h3 = fmaf(bf2f_hi(wv4.y), xk, h3);
    }
    const float4 bb = *reinterpret_cast<const float4*>(b0 + c4);
    float th[4];
    th[0] = tanhf(h0 + bb.x);
    th[1] = tanhf(h1 + bb.y);
    th[2] = tanhf(h2 + bb.z);
    th[3] = tanhf(h3 + bb.w);
    float pr[8] = {};
#pragma unroll
    for (int r = 0; r < 4; ++r) {
        const float4 pA = *reinterpret_cast<const float4*>(pv + (size_t)(c4 + r) * 8);
        const float4 pB = *reinterpret_cast<const float4*>(pv + (size_t)(c4 + r) * 8 + 4);
        pr[0] = fmaf(th[r], pA.x, pr[0]);
        pr[1] = fmaf(th[r], pA.y, pr[1]);
        pr[2] = fmaf(th[r], pA.z, pr[2]);
        pr[3] = fmaf(th[r], pA.w, pr[3]);
        pr[4] = fmaf(th[r], pB.x, pr[4]);
        pr[5] = fmaf(th[r], pB.y, pr[5]);
        pr[6] = fmaf(th[r], pB.z, pr[6]);
        pr[7] = fmaf(th[r], pB.w, pr[7]);
    }
#pragma unroll
    for (int off = 1; off < 64; off <<= 1)
#pragma unroll
        for (int p = 0; p < 8; ++p)
            pr[p] += __shfl_xor(pr[p], off);
    if (lane == 0) {
        float4* dst = reinterpret_cast<float4*>(asd1 + (size_t)node * 8);
        dst[0] = make_float4(pr[0], pr[1], pr[2], pr[3]);
        dst[1] = make_float4(pr[4], pr[5], pr[6], pr[7]);
    }
}

// ---------------- layer-1 aggregation + final linear + softmax ----------------
// asd1[n][8] = (as1_0, as1_1, ad1_0, ad1_1, g00, g01, g10, g11)

__global__ __launch_bounds__(256) void agg_final_k(
        const float* __restrict__ asd1, const int* __restrict__ start,
        const int* __restrict__ deg, const int* __restrict__ colv,
        const float* __restrict__ c2, float* __restrict__ out) {
    const int lane = threadIdx.x & 63;
    const int node = blockIdx.x * 4 + (threadIdx.x >> 6);
    if (node >= N_NODES) return;
    const int beg = start[node];
    const int degv = deg[node];
    const float ad0 = asd1[node * 8 + 2];
    const float ad1v = asd1[node * 8 + 3];
    const int* __restrict__ col = colv + beg;

    float s0 = 0.f, s1 = 0.f, A00 = 0.f, A01 = 0.f, A10 = 0.f, A11 = 0.f;
    for (int j = lane; j < degv; j += 64) {
        int s = col[j];
        const float* rs = asd1 + (size_t)s * 8;
        float2 av = *reinterpret_cast<const float2*>(rs);
        float4 gv = *reinterpret_cast<const float4*>(rs + 4);
        float e0 = __expf(lrelu(av.x + ad0));
        float e1 = __expf(lrelu(av.y + ad1v));
        s0 += e0;
        s1 += e1;
        A00 = fmaf(e0, gv.x, A00);
        A01 = fmaf(e0, gv.y, A01);
        A10 = fmaf(e1, gv.z, A10);
        A11 = fmaf(e1, gv.w, A11);
    }
#pragma unroll
    for (int off = 32; off; off >>= 1) {
        s0  += __shfl_xor(s0, off);
        s1  += __shfl_xor(s1, off);
        A00 += __shfl_xor(A00, off);
        A01 += __shfl_xor(A01, off);
        A10 += __shfl_xor(A10, off);
        A11 += __shfl_xor(A11, off);
    }
    if (lane == 0) {
        float i0 = 1.f / (s0 + 1e-16f), i1 = 1.f / (s1 + 1e-16f);
        float z0 = A00 * i0 + A10 * i1 + c2[0];
        float z1 = A01 * i0 + A11 * i1 + c2[1];
        float mx = fmaxf(z0, z1);
        float e0 = __expf(z0 - mx), e1 = __expf(z1 - mx);
        float inv = 1.f / (e0 + e1);
        out[node * 2 + 0] = e0 * inv;
        out[node * 2 + 1] = e1 * inv;
    }
}

// ---------------- launch ----------------

extern "C" void kernel_launch(void* const* d_in, const int* in_sizes, int n_in,
                              void* d_out, int out_size, void* d_ws, size_t ws_size,
                              hipStream_t stream) {
    const float* x        = (const float*)d_in[0];
    const int*   ei       = (const int*)d_in[1];
    const float* W0       = (const float*)d_in[2];
    const float* att_src0 = (const float*)d_in[3];
    const float* att_dst0 = (const float*)d_in[4];
    const float* b0       = (const float*)d_in[5];
    const float* W1       = (const float*)d_in[6];
    const float* att_src1 = (const float*)d_in[7];
    const float* att_dst1 = (const float*)d_in[8];
    const float* b1       = (const float*)d_in[9];
    const float* Wl       = (const float*)d_in[10];
    const float* bl       = (const float*)d_in[11];
    float* out = (float*)d_out;

    // workspace layout
    unsigned short* xb   = (unsigned short*)d_ws;                 // N*128 bf16
    unsigned short* W0b  = xb + (size_t)N_NODES * 128;            // 128*256 bf16
    float* w0buf = (float*)(W0b + 128 * 256);                     // 128*4 f32
    float* pv    = w0buf + 128 * 4;                               // 256*8 f32
    float* as0   = pv + 256 * 8;                                  // N*2
    float* ad0   = as0 + N_NODES * 2;                             // N*2
    float* asd1  = ad0 + N_NODES * 2;                             // N*8
    int*   degp  = (int*)(asd1 + (size_t)N_NODES * 8);            // N*32 (padded)
    int* cursorp = degp + (size_t)N_NODES * 32;                   // N*32 (padded)
    int* deg     = cursorp + (size_t)N_NODES * 32;                // N
    int* start   = deg + N_NODES;                                 // N
    int* total   = start + N_NODES;                               // 1
    float* c2    = (float*)(total + 1);                           // 2
    int* colv    = (int*)(c2 + 2);                                // E + N

    // ---- zero + pushdown-vector precompute ----
    zero_pre_k<<<(N_NODES * 32 / 4 + 255) / 256, 256, 0, stream>>>(
        (uint4*)degp, total, c2, W0, att_src0, att_dst0,
        W1, att_src1, att_dst1, Wl, w0buf, pv);

    // ---- fused prep ----
    prep_k<<<PREP_BLKS, 256, 0, stream>>>(x, xb, W0, W0b, ei, degp,
                                          w0buf, as0, ad0, Wl, b1, bl, c2);

    // ---- CSR offsets + scatter ----
    offsets_k<<<(N_NODES + 255) / 256, 256, 0, stream>>>(degp, start, deg, cursorp, total);
    scatter_k<<<(TOT_E + 255) / 256, 256, 0, stream>>>(ei, cursorp, colv);

    int nn4 = (N_NODES + 3) / 4;

    // ---- layer 0: aggregate x + fused W0 matvec + tanh + projections ----
    agg0x_k<<<nn4, 256, 0, stream>>>(xb, as0, ad0, start, deg, colv,
                                     W0b, b0, pv, asd1);

    // ---- layer 1 aggregation + final linear + softmax ----
    agg_final_k<<<nn4, 256, 0, stream>>>(asd1, start, deg, colv, c2, out);
}

// Round 20
// 260.548 us; speedup vs baseline: 1.5372x; 1.5372x over previous
//
#include <hip/hip_runtime.h>
#include <math.h>

// Problem constants (from reference)
constexpr int N_NODES = 50000;
constexpr int N_EDGES = 800000;
constexpr int TOT_E   = N_EDGES + N_NODES;   // + self loops
constexpr int HCv     = 256;                 // H*C
constexpr int MAXD    = 256;                 // LDS logit-cache capacity per wave

// GEMM grid geometry
constexpr int GY = (N_NODES + 127) / 128;    // 391 row-tiles (one block each)

// padded atomic counters: one int per 128B line (stride 32 ints)
constexpr int PADSH = 5;

// prep_k section sizes
constexpr int PREP_CVT  = (N_NODES * 128 / 4 + 255) / 256;   // 6250
constexpr int PREP_WT0  = 128;                               // W0 transpose
constexpr int PREP_DEG  = (TOT_E + 255) / 256;               // 3321
constexpr int PREP_ZA   = (N_NODES * 8 / 4 + 255) / 256;     // 391 (zero asd1)
constexpr int PREP_SKIN = (N_NODES + 15) / 16;               // 3125 (as0/ad0 dots)
constexpr int PREP_C    = 1;                                 // c2 = Wl^T b1 + bl
constexpr int PREP_BLKS = PREP_CVT + PREP_WT0 + PREP_DEG + PREP_ZA + PREP_SKIN + PREP_C;

typedef __attribute__((ext_vector_type(8))) short bf16x8;
typedef __attribute__((ext_vector_type(4))) float f32x4;
typedef __attribute__((ext_vector_type(2))) float f32x2;

// ---- bf16 helpers (manual RNE, deterministic) ----
__device__ __forceinline__ unsigned short f2bf(float f) {
    unsigned int u = __float_as_uint(f);
    unsigned int r = (u + 0x7fffu + ((u >> 16) & 1u)) >> 16;
    return (unsigned short)r;
}
__device__ __forceinline__ unsigned int f2bf_pack(float lo, float hi) {
    return (unsigned int)f2bf(lo) | ((unsigned int)f2bf(hi) << 16);
}
__device__ __forceinline__ float bf2f_lo(unsigned int packed) {
    return __uint_as_float(packed << 16);
}
__device__ __forceinline__ float bf2f_hi(unsigned int packed) {
    return __uint_as_float(packed & 0xffff0000u);
}

__device__ __forceinline__ float lrelu(float x) { return x > 0.f ? x : 0.2f * x; }

// ---------------- kernel 1: zero padded deg counters + total + c2,
// block 0 additionally precomputes pushdown vectors w0buf/pv ----

__global__ __launch_bounds__(256) void zero_pre_k(uint4* __restrict__ degp4,
        int* __restrict__ total, float* __restrict__ c2,
        const float* __restrict__ W0, const float* __restrict__ att_src0,
        const float* __restrict__ att_dst0,
        const float* __restrict__ W1, const float* __restrict__ att_src1,
        const float* __restrict__ att_dst1, const float* __restrict__ Wl,
        float* __restrict__ w0buf, float* __restrict__ pv) {
    int i = blockIdx.x * blockDim.x + threadIdx.x;
    if (i < N_NODES * 32 / 4) degp4[i] = make_uint4(0, 0, 0, 0);
    if (blockIdx.x == 0) {
        if (threadIdx.x == 0) { *total = 0; c2[0] = 0.f; c2[1] = 0.f; }
        int k = threadIdx.x;                  // 0..255
        // pv[k][0..7]: (vs1_h0, vs1_h1, vd1_h0, vd1_h1, u00, u01, u10, u11)
        float v0 = 0, v1 = 0, v2 = 0, v3 = 0, v4 = 0, v5 = 0, v6 = 0, v7 = 0;
        const float* wr = W1 + (size_t)k * 256;
        for (int c = 0; c < 128; ++c) {
            float wv = wr[c];
            v0 = fmaf(wv, att_src1[c], v0);
            v2 = fmaf(wv, att_dst1[c], v2);
            v4 = fmaf(wv, Wl[c * 2 + 0], v4);
            v5 = fmaf(wv, Wl[c * 2 + 1], v5);
        }
        for (int c = 128; c < 256; ++c) {
            float wv = wr[c];
            v1 = fmaf(wv, att_src1[c], v1);
            v3 = fmaf(wv, att_dst1[c], v3);
            v6 = fmaf(wv, Wl[c * 2 + 0], v6);
            v7 = fmaf(wv, Wl[c * 2 + 1], v7);
        }
        float* p = pv + (size_t)k * 8;
        p[0] = v0; p[1] = v1; p[2] = v2; p[3] = v3;
        p[4] = v4; p[5] = v5; p[6] = v6; p[7] = v7;
        if (k < 128) {
            // w0buf[k][0..3] = (ws0_h0, ws0_h1, wd0_h0, wd0_h1)
            float w0v = 0, w1v = 0, w2v = 0, w3v = 0;
            const float* wr0 = W0 + (size_t)k * 256;
            for (int c = 0; c < 128; ++c) {
                float wv = wr0[c];
                w0v = fmaf(wv, att_src0[c], w0v);
                w2v = fmaf(wv, att_dst0[c], w2v);
            }
            for (int c = 128; c < 256; ++c) {
                float wv = wr0[c];
                w1v = fmaf(wv, att_src0[c], w1v);
                w3v = fmaf(wv, att_dst0[c], w3v);
            }
            float* q = w0buf + (size_t)k * 4;
            q[0] = w0v; q[1] = w1v; q[2] = w2v; q[3] = w3v;
        }
    }
}

// ---------------- kernel 2: fused prep ----------------
// cvt x->xb | WT0 transpose | degree count | zero asd1 | skinny as0/ad0 | c2

__global__ __launch_bounds__(256) void prep_k(const float* __restrict__ x,
        unsigned short* __restrict__ xb, const float* __restrict__ W0,
        unsigned short* __restrict__ WT0, const int* __restrict__ ei,
        int* __restrict__ degp, float* __restrict__ asd1,
        const float* __restrict__ w0buf, float* __restrict__ a_s,
        float* __restrict__ a_d, const float* __restrict__ Wl,
        const float* __restrict__ b1, const float* __restrict__ bl,
        float* __restrict__ c2) {
    int b = blockIdx.x;
    if (b < PREP_CVT) {                       // x -> bf16 (float4 quads)
        int i = b * 256 + threadIdx.x;
        if (i < N_NODES * 128 / 4) {
            float4 v = *reinterpret_cast<const float4*>(x + (size_t)i * 4);
            ushort4 o;
            o.x = f2bf(v.x); o.y = f2bf(v.y); o.z = f2bf(v.z); o.w = f2bf(v.w);
            *reinterpret_cast<ushort4*>(xb + (size_t)i * 4) = o;
        }
        return;
    }
    b -= PREP_CVT;
    if (b < PREP_WT0) {                       // WT0[n][k] = bf16(W0[k][n]), K=128
        int idx = b * 256 + threadIdx.x;
        int k = idx >> 8, n = idx & 255;
        WT0[(size_t)n * 128 + k] = f2bf(W0[idx]);
        return;
    }
    b -= PREP_WT0;
    if (b < PREP_DEG) {                       // degree count (padded counters)
        int e = b * 256 + threadIdx.x;
        if (e < TOT_E) {
            int dst = (e < N_EDGES) ? ei[N_EDGES + e] : (e - N_EDGES);
            atomicAdd(&degp[dst << PADSH], 1);
        }
        return;
    }
    b -= PREP_DEG;
    if (b < PREP_ZA) {                        // zero asd1
        int i = b * 256 + threadIdx.x;
        if (i < N_NODES * 2)
            *reinterpret_cast<float4*>(asd1 + (size_t)i * 4) = make_float4(0, 0, 0, 0);
        return;
    }
    b -= PREP_ZA;
    if (b < PREP_SKIN) {                      // as0/ad0 = x . w0buf  (16 nodes/block)
        int lane = threadIdx.x & 63;
        int sub = lane >> 4;
        int lq = lane & 15;
        int node = b * 16 + (threadIdx.x >> 6) * 4 + sub;
        if (node < N_NODES) {
            const float* xr = x + (size_t)node * 128 + lq * 8;
            const float4* wv = reinterpret_cast<const float4*>(w0buf) + lq * 8;
            float s0 = 0, s1 = 0, d0 = 0, d1 = 0;
#pragma unroll
            for (int t = 0; t < 8; ++t) {
                float xv = xr[t];
                float4 w = wv[t];
                s0 = fmaf(xv, w.x, s0);
                s1 = fmaf(xv, w.y, s1);
                d0 = fmaf(xv, w.z, d0);
                d1 = fmaf(xv, w.w, d1);
            }
#pragma unroll
            for (int off = 1; off < 16; off <<= 1) {
                s0 += __shfl_xor(s0, off);
                s1 += __shfl_xor(s1, off);
                d0 += __shfl_xor(d0, off);
                d1 += __shfl_xor(d1, off);
            }
            if (lq == 0) {
                *reinterpret_cast<float2*>(a_s + node * 2) = make_float2(s0, s1);
                *reinterpret_cast<float2*>(a_d + node * 2) = make_float2(d0, d1);
            }
        }
        return;
    }
    {                                         // c2 = Wl^T b1 + bl (one block)
        int k = threadIdx.x;
        int lane = k & 63;
        float bv = b1[k];
        float p0 = bv * Wl[k * 2 + 0];
        float p1 = bv * Wl[k * 2 + 1];
        if (k == 0) { p0 += bl[0]; p1 += bl[1]; }
#pragma unroll
        for (int off = 32; off; off >>= 1) {
            p0 += __shfl_xor(p0, off);
            p1 += __shfl_xor(p1, off);
        }
        if (lane == 0) {
            atomicAdd(&c2[0], p0);
            atomicAdd(&c2[1], p1);
        }
    }
}

// ---------------- CSR build ----------------

__global__ void offsets_k(const int* __restrict__ degp, int* __restrict__ start,
                          int* __restrict__ deg, int* __restrict__ cursorp,
                          int* __restrict__ total) {
    int lane = threadIdx.x & 63;
    int node = blockIdx.x * blockDim.x + threadIdx.x;
    int d = (node < N_NODES) ? degp[node << PADSH] : 0;
    int pre = d;
#pragma unroll
    for (int off = 1; off < 64; off <<= 1) {
        int v = __shfl_up(pre, off);
        if (lane >= off) pre += v;
    }
    int wtot = __shfl(pre, 63);
    int base = 0;
    if (lane == 63) base = atomicAdd(total, wtot);
    base = __shfl(base, 63);
    int my = base + pre - d;
    if (node < N_NODES) {
        start[node] = my;
        deg[node] = d;
        cursorp[node << PADSH] = my;
    }
}

__global__ void scatter_k(const int* __restrict__ ei, int* __restrict__ cursorp,
                          int* __restrict__ colv) {
    int e = blockIdx.x * blockDim.x + threadIdx.x;
    if (e >= TOT_E) return;
    int srcv, dstv;
    if (e < N_EDGES) { srcv = ei[e]; dstv = ei[N_EDGES + e]; }
    else             { srcv = dstv = e - N_EDGES; }
    int pos = atomicAdd(&cursorp[dstv << PADSH], 1);
    colv[pos] = srcv;
}

// ---------------- layer-0 aggregation over x (dual-head, 256B/edge) ----------

__global__ __launch_bounds__(256) void agg0x_k(const unsigned short* __restrict__ xb,
                      const float* __restrict__ a_s, const float* __restrict__ a_d,
                      const int* __restrict__ start, const int* __restrict__ deg,
                      const int* __restrict__ colv,
                      unsigned short* __restrict__ xagg) {
    __shared__ float lexp[4][MAXD][2];
    const int lane = threadIdx.x & 63;
    const int wslot = threadIdx.x >> 6;
    const int node = blockIdx.x * 4 + wslot;
    if (node >= N_NODES) return;
    const int beg = start[node];
    const int degv = deg[node];
    const float ad0 = a_d[node * 2], ad1 = a_d[node * 2 + 1];
    const int* __restrict__ col = colv + beg;

    if (degv <= MAXD) {
        // ---- pass A: gather a_s, exp (max-free), stash to LDS, sum ----
        float s0 = 0.f, s1 = 0.f;
        for (int j = lane; j < degv; j += 64) {
            int s = col[j];
            float2 av = *reinterpret_cast<const float2*>(a_s + s * 2);
            float e0 = __expf(lrelu(av.x + ad0));
            float e1 = __expf(lrelu(av.y + ad1));
            *reinterpret_cast<float2*>(&lexp[wslot][j][0]) = make_float2(e0, e1);
            s0 += e0;
            s1 += e1;
        }
#pragma unroll
        for (int off = 32; off; off >>= 1) {
            s0 += __shfl_xor(s0, off);
            s1 += __shfl_xor(s1, off);
        }
        const float inv0 = 1.f / (s0 + 1e-16f);
        const float inv1 = 1.f / (s1 + 1e-16f);

        // ---- pass B: 4 edges/iter; quarter q owns edge 4i+q; lane covers
        // 8 x-channels [lq*8, lq*8+8); dual (e0,e1)-weighted accumulate ----
        const int q = lane >> 4;
        const int lq = lane & 15;
        const unsigned short* __restrict__ xp = xb + lq * 8;
        f32x2 aA[4] = {};   // e0-weighted
        f32x2 aB[4] = {};   // e1-weighted
        const int full = degv >> 2;
        for (int i = 0; i < full; ++i) {
            const int j = 4 * i + q;
            const int s = col[j];
            float2 ee = *reinterpret_cast<float2*>(&lexp[wslot][j][0]);
            const uint4 hv = *reinterpret_cast<const uint4*>(xp + (size_t)s * 128);
            const f32x2 al0 = {ee.x, ee.x};
            const f32x2 al1 = {ee.y, ee.y};
            f32x2 p;
            p.x = bf2f_lo(hv.x); p.y = bf2f_hi(hv.x);
            aA[0] = __builtin_elementwise_fma(p, al0, aA[0]);
            aB[0] = __builtin_elementwise_fma(p, al1, aB[0]);
            p.x = bf2f_lo(hv.y); p.y = bf2f_hi(hv.y);
            aA[1] = __builtin_elementwise_fma(p, al0, aA[1]);
            aB[1] = __builtin_elementwise_fma(p, al1, aB[1]);
            p.x = bf2f_lo(hv.z); p.y = bf2f_hi(hv.z);
            aA[2] = __builtin_elementwise_fma(p, al0, aA[2]);
            aB[2] = __builtin_elementwise_fma(p, al1, aB[2]);
            p.x = bf2f_lo(hv.w); p.y = bf2f_hi(hv.w);
            aA[3] = __builtin_elementwise_fma(p, al0, aA[3]);
            aB[3] = __builtin_elementwise_fma(p, al1, aB[3]);
        }
        {   // tail (degv & 3 edges)
            const int j = full * 4 + q;
            if (j < degv) {
                const int s = col[j];
                float2 ee = *reinterpret_cast<float2*>(&lexp[wslot][j][0]);
                const uint4 hv = *reinterpret_cast<const uint4*>(xp + (size_t)s * 128);
                const f32x2 al0 = {ee.x, ee.x};
                const f32x2 al1 = {ee.y, ee.y};
                f32x2 p;
                p.x = bf2f_lo(hv.x); p.y = bf2f_hi(hv.x);
                aA[0] = __builtin_elementwise_fma(p, al0, aA[0]);
                aB[0] = __builtin_elementwise_fma(p, al1, aB[0]);
                p.x = bf2f_lo(hv.y); p.y = bf2f_hi(hv.y);
                aA[1] = __builtin_elementwise_fma(p, al0, aA[1]);
                aB[1] = __builtin_elementwise_fma(p, al1, aB[1]);
                p.x = bf2f_lo(hv.z); p.y = bf2f_hi(hv.z);
                aA[2] = __builtin_elementwise_fma(p, al0, aA[2]);
                aB[2] = __builtin_elementwise_fma(p, al1, aB[2]);
                p.x = bf2f_lo(hv.w); p.y = bf2f_hi(hv.w);
                aA[3] = __builtin_elementwise_fma(p, al0, aA[3]);
                aB[3] = __builtin_elementwise_fma(p, al1, aB[3]);
            }
        }
        float acc[16];
#pragma unroll
        for (int c = 0; c < 4; ++c) {
            acc[2 * c]     = aA[c].x;
            acc[2 * c + 1] = aA[c].y;
            acc[8 + 2 * c]     = aB[c].x;
            acc[8 + 2 * c + 1] = aB[c].y;
        }
#pragma unroll
        for (int c = 0; c < 16; ++c) {
            acc[c] += __shfl_xor(acc[c], 16);
            acc[c] += __shfl_xor(acc[c], 32);
        }
        if (lane < 16) {
#pragma unroll
            for (int c = 0; c < 8; ++c)  acc[c] *= inv0;
#pragma unroll
            for (int c = 8; c < 16; ++c) acc[c] *= inv1;
            uint4 v0, v1;
            v0.x = f2bf_pack(acc[0], acc[1]);
            v0.y = f2bf_pack(acc[2], acc[3]);
            v0.z = f2bf_pack(acc[4], acc[5]);
            v0.w = f2bf_pack(acc[6], acc[7]);
            v1.x = f2bf_pack(acc[8], acc[9]);
            v1.y = f2bf_pack(acc[10], acc[11]);
            v1.z = f2bf_pack(acc[12], acc[13]);
            v1.w = f2bf_pack(acc[14], acc[15]);
            *reinterpret_cast<uint4*>(xagg + (size_t)node * 256 + lq * 8) = v0;
            *reinterpret_cast<uint4*>(xagg + (size_t)node * 256 + 128 + lq * 8) = v1;
        }
    } else {
        // ---- fallback: 3-pass max-subtracted; lane covers 2 x-channels ----
        const int end = beg + degv;
        float m0 = -INFINITY, m1 = -INFINITY;
        for (int e = beg + lane; e < end; e += 64) {
            int s = colv[e];
            m0 = fmaxf(m0, lrelu(a_s[s * 2] + ad0));
            m1 = fmaxf(m1, lrelu(a_s[s * 2 + 1] + ad1));
        }
#pragma unroll
        for (int off = 32; off; off >>= 1) {
            m0 = fmaxf(m0, __shfl_xor(m0, off));
            m1 = fmaxf(m1, __shfl_xor(m1, off));
        }
        float s0 = 0.f, s1 = 0.f;
        for (int e = beg + lane; e < end; e += 64) {
            int s = colv[e];
            s0 += __expf(lrelu(a_s[s * 2] + ad0) - m0);
            s1 += __expf(lrelu(a_s[s * 2 + 1] + ad1) - m1);
        }
#pragma unroll
        for (int off = 32; off; off >>= 1) {
            s0 += __shfl_xor(s0, off);
            s1 += __shfl_xor(s1, off);
        }
        float inv0 = 1.f / (s0 + 1e-16f);
        float inv1 = 1.f / (s1 + 1e-16f);
        const int cbase = lane * 2;
        float a00 = 0.f, a01 = 0.f, a10 = 0.f, a11 = 0.f;
        for (int e = beg; e < end; ++e) {
            int s = colv[e];
            float2 av = *reinterpret_cast<const float2*>(a_s + s * 2);
            float al0 = __expf(lrelu(av.x + ad0) - m0) * inv0;
            float al1 = __expf(lrelu(av.y + ad1) - m1) * inv1;
            unsigned int xv = *reinterpret_cast<const unsigned int*>(
                xb + (size_t)s * 128 + cbase);
            float x0 = bf2f_lo(xv), x1 = bf2f_hi(xv);
            a00 = fmaf(x0, al0, a00);
            a01 = fmaf(x1, al0, a01);
            a10 = fmaf(x0, al1, a10);
            a11 = fmaf(x1, al1, a11);
        }
        *reinterpret_cast<unsigned int*>(xagg + (size_t)node * 256 + cbase) =
            f2bf_pack(a00, a01);
        *reinterpret_cast<unsigned int*>(xagg + (size_t)node * 256 + 128 + cbase) =
            f2bf_pack(a10, a11);
    }
}

// ---------------- GEMM: hact = tanh(xagg_h @ W0 + b0) in-register, then 8
// projection dots -> asd1[n][8]. One block owns ALL 256 cols of its 128 rows:
// head-loop over two 128-col GEMMs, per-row results combined in-thread.
// NO atomics — single writer per row.

__global__ __launch_bounds__(256) void gemm_tanh_k(
        const unsigned short* __restrict__ A,   // xagg [M][256] bf16
        const unsigned short* __restrict__ BT,  // WT0 [256][128] bf16
        const float* __restrict__ b0,
        const float* __restrict__ pv,           // [256][8] fp32
        float* __restrict__ asd1, int M) {
    const int gy = blockIdx.x;
    const int lane = threadIdx.x & 63;
    const int wv = threadIdx.x >> 6;
    const int lm = lane & 15;
    const int g8 = (lane >> 4) * 8;
    const int row0 = gy * 128 + wv * 32;

    int ra0 = row0 + lm;       if (ra0 >= M) ra0 = M - 1;
    int ra1 = row0 + 16 + lm;  if (ra1 >= M) ra1 = M - 1;

#pragma unroll
    for (int head = 0; head < 2; ++head) {
        const unsigned short* pa0 = A + (size_t)ra0 * 256 + head * 128 + g8;
        const unsigned short* pa1 = A + (size_t)ra1 * 256 + head * 128 + g8;
        const unsigned short* pb  = BT + (size_t)(head * 128 + lm) * 128 + g8;

        f32x4 acc[2][8] = {};
#pragma unroll
        for (int kt = 0; kt < 128; kt += 32) {
            bf16x8 a0 = *reinterpret_cast<const bf16x8*>(pa0 + kt);
            bf16x8 a1 = *reinterpret_cast<const bf16x8*>(pa1 + kt);
#pragma unroll
            for (int j = 0; j < 8; ++j) {
                bf16x8 bf = *reinterpret_cast<const bf16x8*>(
                    pb + (size_t)j * 16 * 128 + kt);
                acc[0][j] = __builtin_amdgcn_mfma_f32_16x16x32_bf16(a0, bf, acc[0][j], 0, 0, 0);
                acc[1][j] = __builtin_amdgcn_mfma_f32_16x16x32_bf16(a1, bf, acc[1][j], 0, 0, 0);
            }
        }

#pragma unroll
        for (int i = 0; i < 2; ++i) {
            float pr[8][4];
#pragma unroll
            for (int p = 0; p < 8; ++p)
#pragma unroll
                for (int r = 0; r < 4; ++r) pr[p][r] = 0.f;
#pragma unroll
            for (int j = 0; j < 8; ++j) {
                const int c = head * 128 + j * 16 + lm;
                const float bc = b0[c];
                const float4 pA = *reinterpret_cast<const float4*>(pv + (size_t)c * 8);
                const float4 pB = *reinterpret_cast<const float4*>(pv + (size_t)c * 8 + 4);
#pragma unroll
                for (int r = 0; r < 4; ++r) {
                    float th = tanhf(acc[i][j][r] + bc);
                    pr[0][r] = fmaf(th, pA.x, pr[0][r]);
                    pr[1][r] = fmaf(th, pA.y, pr[1][r]);
                    pr[2][r] = fmaf(th, pA.z, pr[2][r]);
                    pr[3][r] = fmaf(th, pA.w, pr[3][r]);
                    pr[4][r] = fmaf(th, pB.x, pr[4][r]);
                    pr[5][r] = fmaf(th, pB.y, pr[5][r]);
                    pr[6][r] = fmaf(th, pB.z, pr[6][r]);
                    pr[7][r] = fmaf(th, pB.w, pr[7][r]);
                }
            }
#pragma unroll
            for (int off = 1; off < 16; off <<= 1)
#pragma unroll
                for (int p = 0; p < 8; ++p)
#pragma unroll
                    for (int r = 0; r < 4; ++r)
                        pr[p][r] += __shfl_xor(pr[p][r], off);
            if (lm == 0) {
                int rb = row0 + i * 16 + (lane >> 4) * 4;
#pragma unroll
                for (int r = 0; r < 4; ++r) {
                    if (rb + r < M) {
                        float4* dst = reinterpret_cast<float4*>(asd1 + (size_t)(rb + r) * 8);
                        float4 lo = make_float4(pr[0][r], pr[1][r], pr[2][r], pr[3][r]);
                        float4 hi = make_float4(pr[4][r], pr[5][r], pr[6][r], pr[7][r]);
                        if (head == 0) {
                            dst[0] = lo;
                            dst[1] = hi;
                        } else {
                            float4 o0 = dst[0], o1 = dst[1];
                            o0.x += lo.x; o0.y += lo.y; o0.z += lo.z; o0.w += lo.w;
                            o1.x += hi.x; o1.y += hi.y; o1.z += hi.z; o1.w += hi.w;
                            dst[0] = o0;
                            dst[1] = o1;
                        }
                    }
                }
            }
        }
    }
}

// ---------------- layer-1 aggregation + final linear + softmax ----------------
// asd1[n][8] = (as1_0, as1_1, ad1_0, ad1_1, g00, g01, g10, g11)

__global__ __launch_bounds__(256) void agg_final_k(
        const float* __restrict__ asd1, const int* __restrict__ start,
        const int* __restrict__ deg, const int* __restrict__ colv,
        const float* __restrict__ c2, float* __restrict__ out) {
    const int lane = threadIdx.x & 63;
    const int node = blockIdx.x * 4 + (threadIdx.x >> 6);
    if (node >= N_NODES) return;
    const int beg = start[node];
    const int degv = deg[node];
    const float ad0 = asd1[node * 8 + 2];
    const float ad1v = asd1[node * 8 + 3];
    const int* __restrict__ col = colv + beg;

    float s0 = 0.f, s1 = 0.f, A00 = 0.f, A01 = 0.f, A10 = 0.f, A11 = 0.f;
    for (int j = lane; j < degv; j += 64) {
        int s = col[j];
        const float* rs = asd1 + (size_t)s * 8;
        float2 av = *reinterpret_cast<const float2*>(rs);
        float4 gv = *reinterpret_cast<const float4*>(rs + 4);
        float e0 = __expf(lrelu(av.x + ad0));
        float e1 = __expf(lrelu(av.y + ad1v));
        s0 += e0;
        s1 += e1;
        A00 = fmaf(e0, gv.x, A00);
        A01 = fmaf(e0, gv.y, A01);
        A10 = fmaf(e1, gv.z, A10);
        A11 = fmaf(e1, gv.w, A11);
    }
#pragma unroll
    for (int off = 32; off; off >>= 1) {
        s0  += __shfl_xor(s0, off);
        s1  += __shfl_xor(s1, off);
        A00 += __shfl_xor(A00, off);
        A01 += __shfl_xor(A01, off);
        A10 += __shfl_xor(A10, off);
        A11 += __shfl_xor(A11, off);
    }
    if (lane == 0) {
        float i0 = 1.f / (s0 + 1e-16f), i1 = 1.f / (s1 + 1e-16f);
        float z0 = A00 * i0 + A10 * i1 + c2[0];
        float z1 = A01 * i0 + A11 * i1 + c2[1];
        float mx = fmaxf(z0, z1);
        float e0 = __expf(z0 - mx), e1 = __expf(z1 - mx);
        float inv = 1.f / (e0 + e1);
        out[node * 2 + 0] = e0 * inv;
        out[node * 2 + 1] = e1 * inv;
    }
}

// ---------------- launch ----------------

extern "C" void kernel_launch(void* const* d_in, const int* in_sizes, int n_in,
                              void* d_out, int out_size, void* d_ws, size_t ws_size,
                              hipStream_t stream) {
    const float* x        = (const float*)d_in[0];
    const int*   ei       = (const int*)d_in[1];
    const float* W0       = (const float*)d_in[2];
    const float* att_src0 = (const float*)d_in[3];
    const float* att_dst0 = (const float*)d_in[4];
    const float* b0       = (const float*)d_in[5];
    const float* W1       = (const float*)d_in[6];
    const float* att_src1 = (const float*)d_in[7];
    const float* att_dst1 = (const float*)d_in[8];
    const float* b1       = (const float*)d_in[9];
    const float* Wl       = (const float*)d_in[10];
    const float* bl       = (const float*)d_in[11];
    float* out = (float*)d_out;

    // workspace layout
    unsigned short* xb   = (unsigned short*)d_ws;                 // N*128 bf16
    unsigned short* xagg = xb + (size_t)N_NODES * 128;            // N*256 bf16
    unsigned short* WT0  = xagg + (size_t)N_NODES * 256;          // 256*128 bf16
    float* w0buf = (float*)(WT0 + 256 * 128);                     // 128*4 f32
    float* pv    = w0buf + 128 * 4;                               // 256*8 f32
    float* as0   = pv + 256 * 8;                                  // N*2
    float* ad0   = as0 + N_NODES * 2;                             // N*2
    float* asd1  = ad0 + N_NODES * 2;                             // N*8
    int*   degp  = (int*)(asd1 + (size_t)N_NODES * 8);            // N*32 (padded)
    int* cursorp = degp + (size_t)N_NODES * 32;                   // N*32 (padded)
    int* deg     = cursorp + (size_t)N_NODES * 32;                // N
    int* start   = deg + N_NODES;                                 // N
    int* total   = start + N_NODES;                               // 1
    float* c2    = (float*)(total + 1);                           // 2
    int* colv    = (int*)(c2 + 2);                                // E + N

    // ---- zero + pushdown-vector precompute ----
    zero_pre_k<<<(N_NODES * 32 / 4 + 255) / 256, 256, 0, stream>>>(
        (uint4*)degp, total, c2, W0, att_src0, att_dst0,
        W1, att_src1, att_dst1, Wl, w0buf, pv);

    // ---- fused prep ----
    prep_k<<<PREP_BLKS, 256, 0, stream>>>(x, xb, W0, WT0, ei, degp, asd1,
                                          w0buf, as0, ad0, Wl, b1, bl, c2);

    // ---- CSR offsets + scatter ----
    offsets_k<<<(N_NODES + 255) / 256, 256, 0, stream>>>(degp, start, deg, cursorp, total);
    scatter_k<<<(TOT_E + 255) / 256, 256, 0, stream>>>(ei, cursorp, colv);

    int nn4 = (N_NODES + 3) / 4;

    // ---- layer 0: aggregate x (dual-head), then GEMM+tanh+projections ----
    agg0x_k<<<nn4, 256, 0, stream>>>(xb, as0, ad0, start, deg, colv, xagg);
    gemm_tanh_k<<<GY, 256, 0, stream>>>(xagg, WT0, b0, pv, asd1, N_NODES);

    // ---- layer 1 aggregation + final linear + softmax ----
    agg_final_k<<<nn4, 256, 0, stream>>>(asd1, start, deg, colv, c2, out);
}

// Round 21
// 254.244 us; speedup vs baseline: 1.5753x; 1.0248x over previous
//
#include <hip/hip_runtime.h>
#include <math.h>

// Problem constants (from reference)
constexpr int N_NODES = 50000;
constexpr int N_EDGES = 800000;
constexpr int TOT_E   = N_EDGES + N_NODES;   // + self loops
constexpr int MAXD    = 256;                 // LDS logit-cache capacity per wave

// GEMM grid geometry: 128 rows x 64 cols per block (R14-proven shape)
constexpr int GY      = (N_NODES + 127) / 128;  // 391 row-tiles
constexpr int GT_BLKS = GY * 4;                 // 1564 blocks

// padded atomic counters: one int per 128B line (stride 32 ints)
constexpr int PADSH = 5;

// prep_k section sizes
constexpr int PREP_CVT  = (N_NODES * 128 / 4 + 255) / 256;   // 6250
constexpr int PREP_WT0  = 128;                               // W0 transpose
constexpr int PREP_DEG  = (TOT_E + 255) / 256;               // 3321
constexpr int PREP_SKIN = (N_NODES + 15) / 16;               // 3125 (as0/ad0 dots)
constexpr int PREP_C    = 1;                                 // c2 = Wl^T b1 + bl
constexpr int PREP_BLKS = PREP_CVT + PREP_WT0 + PREP_DEG + PREP_SKIN + PREP_C;

typedef __attribute__((ext_vector_type(8))) short bf16x8;
typedef __attribute__((ext_vector_type(4))) float f32x4;
typedef __attribute__((ext_vector_type(2))) float f32x2;

// ---- bf16 helpers (manual RNE, deterministic) ----
__device__ __forceinline__ unsigned short f2bf(float f) {
    unsigned int u = __float_as_uint(f);
    unsigned int r = (u + 0x7fffu + ((u >> 16) & 1u)) >> 16;
    return (unsigned short)r;
}
__device__ __forceinline__ unsigned int f2bf_pack(float lo, float hi) {
    return (unsigned int)f2bf(lo) | ((unsigned int)f2bf(hi) << 16);
}
__device__ __forceinline__ float bf2f_lo(unsigned int packed) {
    return __uint_as_float(packed << 16);
}
__device__ __forceinline__ float bf2f_hi(unsigned int packed) {
    return __uint_as_float(packed & 0xffff0000u);
}

__device__ __forceinline__ float lrelu(float x) { return x > 0.f ? x : 0.2f * x; }

// ---------------- kernel 1: zero padded deg counters + total + c2,
// block 0 additionally precomputes pushdown vectors w0buf/pv ----

__global__ __launch_bounds__(256) void zero_pre_k(uint4* __restrict__ degp4,
        int* __restrict__ total, float* __restrict__ c2,
        const float* __restrict__ W0, const float* __restrict__ att_src0,
        const float* __restrict__ att_dst0,
        const float* __restrict__ W1, const float* __restrict__ att_src1,
        const float* __restrict__ att_dst1, const float* __restrict__ Wl,
        float* __restrict__ w0buf, float* __restrict__ pv) {
    int i = blockIdx.x * blockDim.x + threadIdx.x;
    if (i < N_NODES * 32 / 4) degp4[i] = make_uint4(0, 0, 0, 0);
    if (blockIdx.x == 0) {
        if (threadIdx.x == 0) { *total = 0; c2[0] = 0.f; c2[1] = 0.f; }
        int k = threadIdx.x;                  // 0..255
        // pv[k][0..7]: (vs1_h0, vs1_h1, vd1_h0, vd1_h1, u00, u01, u10, u11)
        float v0 = 0, v1 = 0, v2 = 0, v3 = 0, v4 = 0, v5 = 0, v6 = 0, v7 = 0;
        const float* wr = W1 + (size_t)k * 256;
        for (int c = 0; c < 128; ++c) {
            float wv = wr[c];
            v0 = fmaf(wv, att_src1[c], v0);
            v2 = fmaf(wv, att_dst1[c], v2);
            v4 = fmaf(wv, Wl[c * 2 + 0], v4);
            v5 = fmaf(wv, Wl[c * 2 + 1], v5);
        }
        for (int c = 128; c < 256; ++c) {
            float wv = wr[c];
            v1 = fmaf(wv, att_src1[c], v1);
            v3 = fmaf(wv, att_dst1[c], v3);
            v6 = fmaf(wv, Wl[c * 2 + 0], v6);
            v7 = fmaf(wv, Wl[c * 2 + 1], v7);
        }
        float* p = pv + (size_t)k * 8;
        p[0] = v0; p[1] = v1; p[2] = v2; p[3] = v3;
        p[4] = v4; p[5] = v5; p[6] = v6; p[7] = v7;
        if (k < 128) {
            // w0buf[k][0..3] = (ws0_h0, ws0_h1, wd0_h0, wd0_h1)
            float w0v = 0, w1v = 0, w2v = 0, w3v = 0;
            const float* wr0 = W0 + (size_t)k * 256;
            for (int c = 0; c < 128; ++c) {
                float wv = wr0[c];
                w0v = fmaf(wv, att_src0[c], w0v);
                w2v = fmaf(wv, att_dst0[c], w2v);
            }
            for (int c = 128; c < 256; ++c) {
                float wv = wr0[c];
                w1v = fmaf(wv, att_src0[c], w1v);
                w3v = fmaf(wv, att_dst0[c], w3v);
            }
            float* q = w0buf + (size_t)k * 4;
            q[0] = w0v; q[1] = w1v; q[2] = w2v; q[3] = w3v;
        }
    }
}

// ---------------- kernel 2: fused prep ----------------
// cvt x->xb | WT0 transpose | degree count | skinny as0/ad0 | c2

__global__ __launch_bounds__(256) void prep_k(const float* __restrict__ x,
        unsigned short* __restrict__ xb, const float* __restrict__ W0,
        unsigned short* __restrict__ WT0, const int* __restrict__ ei,
        int* __restrict__ degp,
        const float* __restrict__ w0buf, float* __restrict__ a_s,
        float* __restrict__ a_d, const float* __restrict__ Wl,
        const float* __restrict__ b1, const float* __restrict__ bl,
        float* __restrict__ c2) {
    int b = blockIdx.x;
    if (b < PREP_CVT) {                       // x -> bf16 (float4 quads)
        int i = b * 256 + threadIdx.x;
        if (i < N_NODES * 128 / 4) {
            float4 v = *reinterpret_cast<const float4*>(x + (size_t)i * 4);
            ushort4 o;
            o.x = f2bf(v.x); o.y = f2bf(v.y); o.z = f2bf(v.z); o.w = f2bf(v.w);
            *reinterpret_cast<ushort4*>(xb + (size_t)i * 4) = o;
        }
        return;
    }
    b -= PREP_CVT;
    if (b < PREP_WT0) {                       // WT0[n][k] = bf16(W0[k][n]), K=128
        int idx = b * 256 + threadIdx.x;
        int k = idx >> 8, n = idx & 255;
        WT0[(size_t)n * 128 + k] = f2bf(W0[idx]);
        return;
    }
    b -= PREP_WT0;
    if (b < PREP_DEG) {                       // degree count (padded counters)
        int e = b * 256 + threadIdx.x;
        if (e < TOT_E) {
            int dst = (e < N_EDGES) ? ei[N_EDGES + e] : (e - N_EDGES);
            atomicAdd(&degp[dst << PADSH], 1);
        }
        return;
    }
    b -= PREP_DEG;
    if (b < PREP_SKIN) {                      // as0/ad0 = x . w0buf  (16 nodes/block)
        int lane = threadIdx.x & 63;
        int sub = lane >> 4;
        int lq = lane & 15;
        int node = b * 16 + (threadIdx.x >> 6) * 4 + sub;
        if (node < N_NODES) {
            const float* xr = x + (size_t)node * 128 + lq * 8;
            const float4* wv = reinterpret_cast<const float4*>(w0buf) + lq * 8;
            float s0 = 0, s1 = 0, d0 = 0, d1 = 0;
#pragma unroll
            for (int t = 0; t < 8; ++t) {
                float xv = xr[t];
                float4 w = wv[t];
                s0 = fmaf(xv, w.x, s0);
                s1 = fmaf(xv, w.y, s1);
                d0 = fmaf(xv, w.z, d0);
                d1 = fmaf(xv, w.w, d1);
            }
#pragma unroll
            for (int off = 1; off < 16; off <<= 1) {
                s0 += __shfl_xor(s0, off);
                s1 += __shfl_xor(s1, off);
                d0 += __shfl_xor(d0, off);
                d1 += __shfl_xor(d1, off);
            }
            if (lq == 0) {
                *reinterpret_cast<float2*>(a_s + node * 2) = make_float2(s0, s1);
                *reinterpret_cast<float2*>(a_d + node * 2) = make_float2(d0, d1);
            }
        }
        return;
    }
    {                                         // c2 = Wl^T b1 + bl (one block)
        int k = threadIdx.x;
        int lane = k & 63;
        float bv = b1[k];
        float p0 = bv * Wl[k * 2 + 0];
        float p1 = bv * Wl[k * 2 + 1];
        if (k == 0) { p0 += bl[0]; p1 += bl[1]; }
#pragma unroll
        for (int off = 32; off; off >>= 1) {
            p0 += __shfl_xor(p0, off);
            p1 += __shfl_xor(p1, off);
        }
        if (lane == 0) {
            atomicAdd(&c2[0], p0);
            atomicAdd(&c2[1], p1);
        }
    }
}

// ---------------- CSR build ----------------

__global__ void offsets_k(const int* __restrict__ degp, int* __restrict__ start,
                          int* __restrict__ deg, int* __restrict__ cursorp,
                          int* __restrict__ total) {
    int lane = threadIdx.x & 63;
    int node = blockIdx.x * blockDim.x + threadIdx.x;
    int d = (node < N_NODES) ? degp[node << PADSH] : 0;
    int pre = d;
#pragma unroll
    for (int off = 1; off < 64; off <<= 1) {
        int v = __shfl_up(pre, off);
        if (lane >= off) pre += v;
    }
    int wtot = __shfl(pre, 63);
    int base = 0;
    if (lane == 63) base = atomicAdd(total, wtot);
    base = __shfl(base, 63);
    int my = base + pre - d;
    if (node < N_NODES) {
        start[node] = my;
        deg[node] = d;
        cursorp[node << PADSH] = my;
    }
}

__global__ void scatter_k(const int* __restrict__ ei, int* __restrict__ cursorp,
                          int* __restrict__ colv) {
    int e = blockIdx.x * blockDim.x + threadIdx.x;
    if (e >= TOT_E) return;
    int srcv, dstv;
    if (e < N_EDGES) { srcv = ei[e]; dstv = ei[N_EDGES + e]; }
    else             { srcv = dstv = e - N_EDGES; }
    int pos = atomicAdd(&cursorp[dstv << PADSH], 1);
    colv[pos] = srcv;
}

// ---------------- layer-0 aggregation over x (dual-head, 256B/edge) ----------

__global__ __launch_bounds__(256) void agg0x_k(const unsigned short* __restrict__ xb,
                      const float* __restrict__ a_s, const float* __restrict__ a_d,
                      const int* __restrict__ start, const int* __restrict__ deg,
                      const int* __restrict__ colv,
                      unsigned short* __restrict__ xagg) {
    __shared__ float lexp[4][MAXD][2];
    const int lane = threadIdx.x & 63;
    const int wslot = threadIdx.x >> 6;
    const int node = blockIdx.x * 4 + wslot;
    if (node >= N_NODES) return;
    const int beg = start[node];
    const int degv = deg[node];
    const float ad0 = a_d[node * 2], ad1 = a_d[node * 2 + 1];
    const int* __restrict__ col = colv + beg;

    if (degv <= MAXD) {
        // ---- pass A: gather a_s, exp (max-free), stash to LDS, sum ----
        float s0 = 0.f, s1 = 0.f;
        for (int j = lane; j < degv; j += 64) {
            int s = col[j];
            float2 av = *reinterpret_cast<const float2*>(a_s + s * 2);
            float e0 = __expf(lrelu(av.x + ad0));
            float e1 = __expf(lrelu(av.y + ad1));
            *reinterpret_cast<float2*>(&lexp[wslot][j][0]) = make_float2(e0, e1);
            s0 += e0;
            s1 += e1;
        }
#pragma unroll
        for (int off = 32; off; off >>= 1) {
            s0 += __shfl_xor(s0, off);
            s1 += __shfl_xor(s1, off);
        }
        const float inv0 = 1.f / (s0 + 1e-16f);
        const float inv1 = 1.f / (s1 + 1e-16f);

        // ---- pass B: 4 edges/iter; quarter q owns edge 4i+q; lane covers
        // 8 x-channels [lq*8, lq*8+8); dual (e0,e1)-weighted accumulate ----
        const int q = lane >> 4;
        const int lq = lane & 15;
        const unsigned short* __restrict__ xp = xb + lq * 8;
        f32x2 aA[4] = {};   // e0-weighted
        f32x2 aB[4] = {};   // e1-weighted
        const int full = degv >> 2;
        for (int i = 0; i < full; ++i) {
            const int j = 4 * i + q;
            const int s = col[j];
            float2 ee = *reinterpret_cast<float2*>(&lexp[wslot][j][0]);
            const uint4 hv = *reinterpret_cast<const uint4*>(xp + (size_t)s * 128);
            const f32x2 al0 = {ee.x, ee.x};
            const f32x2 al1 = {ee.y, ee.y};
            f32x2 p;
            p.x = bf2f_lo(hv.x); p.y = bf2f_hi(hv.x);
            aA[0] = __builtin_elementwise_fma(p, al0, aA[0]);
            aB[0] = __builtin_elementwise_fma(p, al1, aB[0]);
            p.x = bf2f_lo(hv.y); p.y = bf2f_hi(hv.y);
            aA[1] = __builtin_elementwise_fma(p, al0, aA[1]);
            aB[1] = __builtin_elementwise_fma(p, al1, aB[1]);
            p.x = bf2f_lo(hv.z); p.y = bf2f_hi(hv.z);
            aA[2] = __builtin_elementwise_fma(p, al0, aA[2]);
            aB[2] = __builtin_elementwise_fma(p, al1, aB[2]);
            p.x = bf2f_lo(hv.w); p.y = bf2f_hi(hv.w);
            aA[3] = __builtin_elementwise_fma(p, al0, aA[3]);
            aB[3] = __builtin_elementwise_fma(p, al1, aB[3]);
        }
        {   // tail (degv & 3 edges)
            const int j = full * 4 + q;
            if (j < degv) {
                const int s = col[j];
                float2 ee = *reinterpret_cast<float2*>(&lexp[wslot][j][0]);
                const uint4 hv = *reinterpret_cast<const uint4*>(xp + (size_t)s * 128);
                const f32x2 al0 = {ee.x, ee.x};
                const f32x2 al1 = {ee.y, ee.y};
                f32x2 p;
                p.x = bf2f_lo(hv.x); p.y = bf2f_hi(hv.x);
                aA[0] = __builtin_elementwise_fma(p, al0, aA[0]);
                aB[0] = __builtin_elementwise_fma(p, al1, aB[0]);
                p.x = bf2f_lo(hv.y); p.y = bf2f_hi(hv.y);
                aA[1] = __builtin_elementwise_fma(p, al0, aA[1]);
                aB[1] = __builtin_elementwise_fma(p, al1, aB[1]);
                p.x = bf2f_lo(hv.z); p.y = bf2f_hi(hv.z);
                aA[2] = __builtin_elementwise_fma(p, al0, aA[2]);
                aB[2] = __builtin_elementwise_fma(p, al1, aB[2]);
                p.x = bf2f_lo(hv.w); p.y = bf2f_hi(hv.w);
                aA[3] = __builtin_elementwise_fma(p, al0, aA[3]);
                aB[3] = __builtin_elementwise_fma(p, al1, aB[3]);
            }
        }
        float acc[16];
#pragma unroll
        for (int c = 0; c < 4; ++c) {
            acc[2 * c]     = aA[c].x;
            acc[2 * c + 1] = aA[c].y;
            acc[8 + 2 * c]     = aB[c].x;
            acc[8 + 2 * c + 1] = aB[c].y;
        }
#pragma unroll
        for (int c = 0; c < 16; ++c) {
            acc[c] += __shfl_xor(acc[c], 16);
            acc[c] += __shfl_xor(acc[c], 32);
        }
        if (lane < 16) {
#pragma unroll
            for (int c = 0; c < 8; ++c)  acc[c] *= inv0;
#pragma unroll
            for (int c = 8; c < 16; ++c) acc[c] *= inv1;
            uint4 v0, v1;
            v0.x = f2bf_pack(acc[0], acc[1]);
            v0.y = f2bf_pack(acc[2], acc[3]);
            v0.z = f2bf_pack(acc[4], acc[5]);
            v0.w = f2bf_pack(acc[6], acc[7]);
            v1.x = f2bf_pack(acc[8], acc[9]);
            v1.y = f2bf_pack(acc[10], acc[11]);
            v1.z = f2bf_pack(acc[12], acc[13]);
            v1.w = f2bf_pack(acc[14], acc[15]);
            *reinterpret_cast<uint4*>(xagg + (size_t)node * 256 + lq * 8) = v0;
            *reinterpret_cast<uint4*>(xagg + (size_t)node * 256 + 128 + lq * 8) = v1;
        }
    } else {
        // ---- fallback: 3-pass max-subtracted; lane covers 2 x-channels ----
        const int end = beg + degv;
        float m0 = -INFINITY, m1 = -INFINITY;
        for (int e = beg + lane; e < end; e += 64) {
            int s = colv[e];
            m0 = fmaxf(m0, lrelu(a_s[s * 2] + ad0));
            m1 = fmaxf(m1, lrelu(a_s[s * 2 + 1] + ad1));
        }
#pragma unroll
        for (int off = 32; off; off >>= 1) {
            m0 = fmaxf(m0, __shfl_xor(m0, off));
            m1 = fmaxf(m1, __shfl_xor(m1, off));
        }
        float s0 = 0.f, s1 = 0.f;
        for (int e = beg + lane; e < end; e += 64) {
            int s = colv[e];
            s0 += __expf(lrelu(a_s[s * 2] + ad0) - m0);
            s1 += __expf(lrelu(a_s[s * 2 + 1] + ad1) - m1);
        }
#pragma unroll
        for (int off = 32; off; off >>= 1) {
            s0 += __shfl_xor(s0, off);
            s1 += __shfl_xor(s1, off);
        }
        float inv0 = 1.f / (s0 + 1e-16f);
        float inv1 = 1.f / (s1 + 1e-16f);
        const int cbase = lane * 2;
        float a00 = 0.f, a01 = 0.f, a10 = 0.f, a11 = 0.f;
        for (int e = beg; e < end; ++e) {
            int s = colv[e];
            float2 av = *reinterpret_cast<const float2*>(a_s + s * 2);
            float al0 = __expf(lrelu(av.x + ad0) - m0) * inv0;
            float al1 = __expf(lrelu(av.y + ad1) - m1) * inv1;
            unsigned int xv = *reinterpret_cast<const unsigned int*>(
                xb + (size_t)s * 128 + cbase);
            float x0 = bf2f_lo(xv), x1 = bf2f_hi(xv);
            a00 = fmaf(x0, al0, a00);
            a01 = fmaf(x1, al0, a01);
            a10 = fmaf(x0, al1, a10);
            a11 = fmaf(x1, al1, a11);
        }
        *reinterpret_cast<unsigned int*>(xagg + (size_t)node * 256 + cbase) =
            f2bf_pack(a00, a01);
        *reinterpret_cast<unsigned int*>(xagg + (size_t)node * 256 + 128 + cbase) =
            f2bf_pack(a10, a11);
    }
}

// ---------------- GEMM: hact = tanh(xagg_h @ W0 + b0) in-register, then this
// block's 64-col slice of the 8 projection dots -> part[cb][row][8].
// R14-proven geometry: 1564 blocks, each 128 rows x 64 cols of one head.
// Plain stores (single writer per (cb,row)); reduce_part_k sums the 4 slices.

__global__ __launch_bounds__(256) void gemm_tanh_k(
        const unsigned short* __restrict__ A,   // xagg [M][256] bf16
        const unsigned short* __restrict__ BT,  // WT0 [256][128] bf16
        const float* __restrict__ b0,
        const float* __restrict__ pv,           // [256][8] fp32
        float* __restrict__ part, int M) {
    const int bid = blockIdx.x;
    const int cb = bid & 3;              // col-block: cols [cb*64, cb*64+64)
    const int gy = bid >> 2;
    const int head = cb >> 1;
    const int lane = threadIdx.x & 63;
    const int wv = threadIdx.x >> 6;
    const int lm = lane & 15;
    const int g8 = (lane >> 4) * 8;
    const int row0 = gy * 128 + wv * 32;
    const int n0 = cb * 64;

    int ra0 = row0 + lm;       if (ra0 >= M) ra0 = M - 1;
    int ra1 = row0 + 16 + lm;  if (ra1 >= M) ra1 = M - 1;
    const unsigned short* pa0 = A + (size_t)ra0 * 256 + head * 128 + g8;
    const unsigned short* pa1 = A + (size_t)ra1 * 256 + head * 128 + g8;
    const unsigned short* pb  = BT + (size_t)(n0 + lm) * 128 + g8;

    f32x4 acc[2][4] = {};
#pragma unroll
    for (int kt = 0; kt < 128; kt += 32) {
        bf16x8 a0 = *reinterpret_cast<const bf16x8*>(pa0 + kt);
        bf16x8 a1 = *reinterpret_cast<const bf16x8*>(pa1 + kt);
        bf16x8 b0f = *reinterpret_cast<const bf16x8*>(pb + kt);
        bf16x8 b1f = *reinterpret_cast<const bf16x8*>(pb + 16 * 128 + kt);
        bf16x8 b2f = *reinterpret_cast<const bf16x8*>(pb + 32 * 128 + kt);
        bf16x8 b3f = *reinterpret_cast<const bf16x8*>(pb + 48 * 128 + kt);
        acc[0][0] = __builtin_amdgcn_mfma_f32_16x16x32_bf16(a0, b0f, acc[0][0], 0, 0, 0);
        acc[0][1] = __builtin_amdgcn_mfma_f32_16x16x32_bf16(a0, b1f, acc[0][1], 0, 0, 0);
        acc[0][2] = __builtin_amdgcn_mfma_f32_16x16x32_bf16(a0, b2f, acc[0][2], 0, 0, 0);
        acc[0][3] = __builtin_amdgcn_mfma_f32_16x16x32_bf16(a0, b3f, acc[0][3], 0, 0, 0);
        acc[1][0] = __builtin_amdgcn_mfma_f32_16x16x32_bf16(a1, b0f, acc[1][0], 0, 0, 0);
        acc[1][1] = __builtin_amdgcn_mfma_f32_16x16x32_bf16(a1, b1f, acc[1][1], 0, 0, 0);
        acc[1][2] = __builtin_amdgcn_mfma_f32_16x16x32_bf16(a1, b2f, acc[1][2], 0, 0, 0);
        acc[1][3] = __builtin_amdgcn_mfma_f32_16x16x32_bf16(a1, b3f, acc[1][3], 0, 0, 0);
    }

    // per-column constants for my 4 col-frags
    float bc[4];
    float4 pA[4], pB[4];
#pragma unroll
    for (int j = 0; j < 4; ++j) {
        int c = n0 + j * 16 + lm;
        bc[j] = b0[c];
        pA[j] = *reinterpret_cast<const float4*>(pv + (size_t)c * 8);
        pB[j] = *reinterpret_cast<const float4*>(pv + (size_t)c * 8 + 4);
    }

#pragma unroll
    for (int i = 0; i < 2; ++i) {
        float pr[8][4];
#pragma unroll
        for (int p = 0; p < 8; ++p)
#pragma unroll
            for (int r = 0; r < 4; ++r) pr[p][r] = 0.f;
#pragma unroll
        for (int j = 0; j < 4; ++j)
#pragma unroll
            for (int r = 0; r < 4; ++r) {
                float th = tanhf(acc[i][j][r] + bc[j]);
                pr[0][r] = fmaf(th, pA[j].x, pr[0][r]);
                pr[1][r] = fmaf(th, pA[j].y, pr[1][r]);
                pr[2][r] = fmaf(th, pA[j].z, pr[2][r]);
                pr[3][r] = fmaf(th, pA[j].w, pr[3][r]);
                pr[4][r] = fmaf(th, pB[j].x, pr[4][r]);
                pr[5][r] = fmaf(th, pB[j].y, pr[5][r]);
                pr[6][r] = fmaf(th, pB[j].z, pr[6][r]);
                pr[7][r] = fmaf(th, pB[j].w, pr[7][r]);
            }
#pragma unroll
        for (int off = 1; off < 16; off <<= 1)
#pragma unroll
            for (int p = 0; p < 8; ++p)
#pragma unroll
                for (int r = 0; r < 4; ++r)
                    pr[p][r] += __shfl_xor(pr[p][r], off);
        if (lm == 0) {
            int rb = row0 + i * 16 + (lane >> 4) * 4;
#pragma unroll
            for (int r = 0; r < 4; ++r) {
                if (rb + r < M) {
                    float4* dst = reinterpret_cast<float4*>(
                        part + ((size_t)cb * N_NODES + rb + r) * 8);
                    dst[0] = make_float4(pr[0][r], pr[1][r], pr[2][r], pr[3][r]);
                    dst[1] = make_float4(pr[4][r], pr[5][r], pr[6][r], pr[7][r]);
                }
            }
        }
    }
}

// ---------------- sum the 4 col-block partials -> asd1[n][8] ----------------

__global__ void reduce_part_k(const float* __restrict__ part,
                              float* __restrict__ asd1) {
    int i = blockIdx.x * blockDim.x + threadIdx.x;
    if (i < N_NODES * 8) {
        const size_t S = (size_t)N_NODES * 8;
        asd1[i] = part[i] + part[i + S] + part[i + 2 * S] + part[i + 3 * S];
    }
}

// ---------------- layer-1 aggregation + final linear + softmax ----------------
// asd1[n][8] = (as1_0, as1_1, ad1_0, ad1_1, g00, g01, g10, g11)

__global__ __launch_bounds__(256) void agg_final_k(
        const float* __restrict__ asd1, const int* __restrict__ start,
        const int* __restrict__ deg, const int* __restrict__ colv,
        const float* __restrict__ c2, float* __restrict__ out) {
    const int lane = threadIdx.x & 63;
    const int node = blockIdx.x * 4 + (threadIdx.x >> 6);
    if (node >= N_NODES) return;
    const int beg = start[node];
    const int degv = deg[node];
    const float ad0 = asd1[node * 8 + 2];
    const float ad1v = asd1[node * 8 + 3];
    const int* __restrict__ col = colv + beg;

    float s0 = 0.f, s1 = 0.f, A00 = 0.f, A01 = 0.f, A10 = 0.f, A11 = 0.f;
    for (int j = lane; j < degv; j += 64) {
        int s = col[j];
        const float* rs = asd1 + (size_t)s * 8;
        float2 av = *reinterpret_cast<const float2*>(rs);
        float4 gv = *reinterpret_cast<const float4*>(rs + 4);
        float e0 = __expf(lrelu(av.x + ad0));
        float e1 = __expf(lrelu(av.y + ad1v));
        s0 += e0;
        s1 += e1;
        A00 = fmaf(e0, gv.x, A00);
        A01 = fmaf(e0, gv.y, A01);
        A10 = fmaf(e1, gv.z, A10);
        A11 = fmaf(e1, gv.w, A11);
    }
#pragma unroll
    for (int off = 32; off; off >>= 1) {
        s0  += __shfl_xor(s0, off);
        s1  += __shfl_xor(s1, off);
        A00 += __shfl_xor(A00, off);
        A01 += __shfl_xor(A01, off);
        A10 += __shfl_xor(A10, off);
        A11 += __shfl_xor(A11, off);
    }
    if (lane == 0) {
        float i0 = 1.f / (s0 + 1e-16f), i1 = 1.f / (s1 + 1e-16f);
        float z0 = A00 * i0 + A10 * i1 + c2[0];
        float z1 = A01 * i0 + A11 * i1 + c2[1];
        float mx = fmaxf(z0, z1);
        float e0 = __expf(z0 - mx), e1 = __expf(z1 - mx);
        float inv = 1.f / (e0 + e1);
        out[node * 2 + 0] = e0 * inv;
        out[node * 2 + 1] = e1 * inv;
    }
}

// ---------------- launch ----------------

extern "C" void kernel_launch(void* const* d_in, const int* in_sizes, int n_in,
                              void* d_out, int out_size, void* d_ws, size_t ws_size,
                              hipStream_t stream) {
    const float* x        = (const float*)d_in[0];
    const int*   ei       = (const int*)d_in[1];
    const float* W0       = (const float*)d_in[2];
    const float* att_src0 = (const float*)d_in[3];
    const float* att_dst0 = (const float*)d_in[4];
    const float* b0       = (const float*)d_in[5];
    const float* W1       = (const float*)d_in[6];
    const float* att_src1 = (const float*)d_in[7];
    const float* att_dst1 = (const float*)d_in[8];
    const float* b1       = (const float*)d_in[9];
    const float* Wl       = (const float*)d_in[10];
    const float* bl       = (const float*)d_in[11];
    float* out = (float*)d_out;

    // workspace layout
    unsigned short* xb   = (unsigned short*)d_ws;                 // N*128 bf16
    unsigned short* xagg = xb + (size_t)N_NODES * 128;            // N*256 bf16
    unsigned short* WT0  = xagg + (size_t)N_NODES * 256;          // 256*128 bf16
    float* w0buf = (float*)(WT0 + 256 * 128);                     // 128*4 f32
    float* pv    = w0buf + 128 * 4;                               // 256*8 f32
    float* as0   = pv + 256 * 8;                                  // N*2
    float* ad0   = as0 + N_NODES * 2;                             // N*2
    float* asd1  = ad0 + N_NODES * 2;                             // N*8
    float* part  = asd1 + (size_t)N_NODES * 8;                    // 4*N*8
    int*   degp  = (int*)(part + (size_t)N_NODES * 32);           // N*32 (padded)
    int* cursorp = degp + (size_t)N_NODES * 32;                   // N*32 (padded)
    int* deg     = cursorp + (size_t)N_NODES * 32;                // N
    int* start   = deg + N_NODES;                                 // N
    int* total   = start + N_NODES;                               // 1
    float* c2    = (float*)(total + 1);                           // 2
    int* colv    = (int*)(c2 + 2);                                // E + N

    // ---- zero + pushdown-vector precompute ----
    zero_pre_k<<<(N_NODES * 32 / 4 + 255) / 256, 256, 0, stream>>>(
        (uint4*)degp, total, c2, W0, att_src0, att_dst0,
        W1, att_src1, att_dst1, Wl, w0buf, pv);

    // ---- fused prep ----
    prep_k<<<PREP_BLKS, 256, 0, stream>>>(x, xb, W0, WT0, ei, degp,
                                          w0buf, as0, ad0, Wl, b1, bl, c2);

    // ---- CSR offsets + scatter ----
    offsets_k<<<(N_NODES + 255) / 256, 256, 0, stream>>>(degp, start, deg, cursorp, total);
    scatter_k<<<(TOT_E + 255) / 256, 256, 0, stream>>>(ei, cursorp, colv);

    int nn4 = (N_NODES + 3) / 4;

    // ---- layer 0: aggregate x (dual-head), then GEMM+tanh+projections ----
    agg0x_k<<<nn4, 256, 0, stream>>>(xb, as0, ad0, start, deg, colv, xagg);
    gemm_tanh_k<<<GT_BLKS, 256, 0, stream>>>(xagg, WT0, b0, pv, part, N_NODES);
    reduce_part_k<<<(N_NODES * 8 + 255) / 256, 256, 0, stream>>>(part, asd1);

    // ---- layer 1 aggregation + final linear + softmax ----
    agg_final_k<<<nn4, 256, 0, stream>>>(asd1, start, deg, colv, c2, out);
}

// Round 22
// 253.568 us; speedup vs baseline: 1.5795x; 1.0027x over previous
//
#include <hip/hip_runtime.h>
#include <math.h>

// Problem constants (from reference)
constexpr int N_NODES = 50000;
constexpr int N_EDGES = 800000;
constexpr int TOT_E   = N_EDGES + N_NODES;   // + self loops
constexpr int MAXD    = 256;                 // LDS logit-cache capacity per wave

// GEMM grid geometry: 64 rows x 64 cols per block (16 rows/wave)
constexpr int GY      = (N_NODES + 63) / 64;    // 782 row-tiles
constexpr int GT_BLKS = GY * 4;                 // 3128 blocks

// padded atomic counters: one int per 128B line (stride 32 ints)
constexpr int PADSH = 5;

// prep_k section sizes
constexpr int PREP_CVT  = (N_NODES * 128 / 4 + 255) / 256;   // 6250
constexpr int PREP_WT0  = 128;                               // W0 transpose
constexpr int PREP_DEG  = (TOT_E + 255) / 256;               // 3321
constexpr int PREP_SKIN = (N_NODES + 15) / 16;               // 3125 (as0/ad0 dots)
constexpr int PREP_C    = 1;                                 // c2 = Wl^T b1 + bl
constexpr int PREP_BLKS = PREP_CVT + PREP_WT0 + PREP_DEG + PREP_SKIN + PREP_C;

typedef __attribute__((ext_vector_type(8))) short bf16x8;
typedef __attribute__((ext_vector_type(4))) float f32x4;
typedef __attribute__((ext_vector_type(2))) float f32x2;

// ---- bf16 helpers (manual RNE, deterministic) ----
__device__ __forceinline__ unsigned short f2bf(float f) {
    unsigned int u = __float_as_uint(f);
    unsigned int r = (u + 0x7fffu + ((u >> 16) & 1u)) >> 16;
    return (unsigned short)r;
}
__device__ __forceinline__ unsigned int f2bf_pack(float lo, float hi) {
    return (unsigned int)f2bf(lo) | ((unsigned int)f2bf(hi) << 16);
}
__device__ __forceinline__ float bf2f_lo(unsigned int packed) {
    return __uint_as_float(packed << 16);
}
__device__ __forceinline__ float bf2f_hi(unsigned int packed) {
    return __uint_as_float(packed & 0xffff0000u);
}

__device__ __forceinline__ float lrelu(float x) { return x > 0.f ? x : 0.2f * x; }

// ---------------- kernel 1: zero padded deg counters + total + c2,
// block 0 additionally precomputes pushdown vectors w0buf/pv ----

__global__ __launch_bounds__(256) void zero_pre_k(uint4* __restrict__ degp4,
        int* __restrict__ total, float* __restrict__ c2,
        const float* __restrict__ W0, const float* __restrict__ att_src0,
        const float* __restrict__ att_dst0,
        const float* __restrict__ W1, const float* __restrict__ att_src1,
        const float* __restrict__ att_dst1, const float* __restrict__ Wl,
        float* __restrict__ w0buf, float* __restrict__ pv) {
    int i = blockIdx.x * blockDim.x + threadIdx.x;
    if (i < N_NODES * 32 / 4) degp4[i] = make_uint4(0, 0, 0, 0);
    if (blockIdx.x == 0) {
        if (threadIdx.x == 0) { *total = 0; c2[0] = 0.f; c2[1] = 0.f; }
        int k = threadIdx.x;                  // 0..255
        // pv[k][0..7]: (vs1_h0, vs1_h1, vd1_h0, vd1_h1, u00, u01, u10, u11)
        float v0 = 0, v1 = 0, v2 = 0, v3 = 0, v4 = 0, v5 = 0, v6 = 0, v7 = 0;
        const float* wr = W1 + (size_t)k * 256;
        for (int c = 0; c < 128; ++c) {
            float wv = wr[c];
            v0 = fmaf(wv, att_src1[c], v0);
            v2 = fmaf(wv, att_dst1[c], v2);
            v4 = fmaf(wv, Wl[c * 2 + 0], v4);
            v5 = fmaf(wv, Wl[c * 2 + 1], v5);
        }
        for (int c = 128; c < 256; ++c) {
            float wv = wr[c];
            v1 = fmaf(wv, att_src1[c], v1);
            v3 = fmaf(wv, att_dst1[c], v3);
            v6 = fmaf(wv, Wl[c * 2 + 0], v6);
            v7 = fmaf(wv, Wl[c * 2 + 1], v7);
        }
        float* p = pv + (size_t)k * 8;
        p[0] = v0; p[1] = v1; p[2] = v2; p[3] = v3;
        p[4] = v4; p[5] = v5; p[6] = v6; p[7] = v7;
        if (k < 128) {
            // w0buf[k][0..3] = (ws0_h0, ws0_h1, wd0_h0, wd0_h1)
            float w0v = 0, w1v = 0, w2v = 0, w3v = 0;
            const float* wr0 = W0 + (size_t)k * 256;
            for (int c = 0; c < 128; ++c) {
                float wv = wr0[c];
                w0v = fmaf(wv, att_src0[c], w0v);
                w2v = fmaf(wv, att_dst0[c], w2v);
            }
            for (int c = 128; c < 256; ++c) {
                float wv = wr0[c];
                w1v = fmaf(wv, att_src0[c], w1v);
                w3v = fmaf(wv, att_dst0[c], w3v);
            }
            float* q = w0buf + (size_t)k * 4;
            q[0] = w0v; q[1] = w1v; q[2] = w2v; q[3] = w3v;
        }
    }
}

// ---------------- kernel 2: fused prep ----------------
// cvt x->xb | WT0 transpose | degree count | skinny as0/ad0 | c2

__global__ __launch_bounds__(256) void prep_k(const float* __restrict__ x,
        unsigned short* __restrict__ xb, const float* __restrict__ W0,
        unsigned short* __restrict__ WT0, const int* __restrict__ ei,
        int* __restrict__ degp,
        const float* __restrict__ w0buf, float* __restrict__ a_s,
        float* __restrict__ a_d, const float* __restrict__ Wl,
        const float* __restrict__ b1, const float* __restrict__ bl,
        float* __restrict__ c2) {
    int b = blockIdx.x;
    if (b < PREP_CVT) {                       // x -> bf16 (float4 quads)
        int i = b * 256 + threadIdx.x;
        if (i < N_NODES * 128 / 4) {
            float4 v = *reinterpret_cast<const float4*>(x + (size_t)i * 4);
            ushort4 o;
            o.x = f2bf(v.x); o.y = f2bf(v.y); o.z = f2bf(v.z); o.w = f2bf(v.w);
            *reinterpret_cast<ushort4*>(xb + (size_t)i * 4) = o;
        }
        return;
    }
    b -= PREP_CVT;
    if (b < PREP_WT0) {                       // WT0[n][k] = bf16(W0[k][n]), K=128
        int idx = b * 256 + threadIdx.x;
        int k = idx >> 8, n = idx & 255;
        WT0[(size_t)n * 128 + k] = f2bf(W0[idx]);
        return;
    }
    b -= PREP_WT0;
    if (b < PREP_DEG) {                       // degree count (padded counters)
        int e = b * 256 + threadIdx.x;
        if (e < TOT_E) {
            int dst = (e < N_EDGES) ? ei[N_EDGES + e] : (e - N_EDGES);
            atomicAdd(&degp[dst << PADSH], 1);
        }
        return;
    }
    b -= PREP_DEG;
    if (b < PREP_SKIN) {                      // as0/ad0 = x . w0buf  (16 nodes/block)
        int lane = threadIdx.x & 63;
        int sub = lane >> 4;
        int lq = lane & 15;
        int node = b * 16 + (threadIdx.x >> 6) * 4 + sub;
        if (node < N_NODES) {
            const float* xr = x + (size_t)node * 128 + lq * 8;
            const float4* wv = reinterpret_cast<const float4*>(w0buf) + lq * 8;
            float s0 = 0, s1 = 0, d0 = 0, d1 = 0;
#pragma unroll
            for (int t = 0; t < 8; ++t) {
                float xv = xr[t];
                float4 w = wv[t];
                s0 = fmaf(xv, w.x, s0);
                s1 = fmaf(xv, w.y, s1);
                d0 = fmaf(xv, w.z, d0);
                d1 = fmaf(xv, w.w, d1);
            }
#pragma unroll
            for (int off = 1; off < 16; off <<= 1) {
                s0 += __shfl_xor(s0, off);
                s1 += __shfl_xor(s1, off);
                d0 += __shfl_xor(d0, off);
                d1 += __shfl_xor(d1, off);
            }
            if (lq == 0) {
                *reinterpret_cast<float2*>(a_s + node * 2) = make_float2(s0, s1);
                *reinterpret_cast<float2*>(a_d + node * 2) = make_float2(d0, d1);
            }
        }
        return;
    }
    {                                         // c2 = Wl^T b1 + bl (one block)
        int k = threadIdx.x;
        int lane = k & 63;
        float bv = b1[k];
        float p0 = bv * Wl[k * 2 + 0];
        float p1 = bv * Wl[k * 2 + 1];
        if (k == 0) { p0 += bl[0]; p1 += bl[1]; }
#pragma unroll
        for (int off = 32; off; off >>= 1) {
            p0 += __shfl_xor(p0, off);
            p1 += __shfl_xor(p1, off);
        }
        if (lane == 0) {
            atomicAdd(&c2[0], p0);
            atomicAdd(&c2[1], p1);
        }
    }
}

// ---------------- CSR build ----------------

__global__ void offsets_k(const int* __restrict__ degp, int* __restrict__ start,
                          int* __restrict__ deg, int* __restrict__ cursorp,
                          int* __restrict__ total) {
    int lane = threadIdx.x & 63;
    int node = blockIdx.x * blockDim.x + threadIdx.x;
    int d = (node < N_NODES) ? degp[node << PADSH] : 0;
    int pre = d;
#pragma unroll
    for (int off = 1; off < 64; off <<= 1) {
        int v = __shfl_up(pre, off);
        if (lane >= off) pre += v;
    }
    int wtot = __shfl(pre, 63);
    int base = 0;
    if (lane == 63) base = atomicAdd(total, wtot);
    base = __shfl(base, 63);
    int my = base + pre - d;
    if (node < N_NODES) {
        start[node] = my;
        deg[node] = d;
        cursorp[node << PADSH] = my;
    }
}

// 4 edges per thread: 4 independent atomic->store chains in flight.
__global__ __launch_bounds__(256) void scatter_k(const int* __restrict__ ei,
                                                 int* __restrict__ cursorp,
                                                 int* __restrict__ colv) {
    const int t = blockIdx.x * 256 + threadIdx.x;
    const int e0 = t * 4;
    if (e0 >= TOT_E) return;
    int srcs[4], dsts[4];
    if (e0 + 3 < N_EDGES) {                  // vector fast path (edge region)
        int4 sv = *reinterpret_cast<const int4*>(ei + e0);
        int4 dv = *reinterpret_cast<const int4*>(ei + N_EDGES + e0);
        srcs[0] = sv.x; srcs[1] = sv.y; srcs[2] = sv.z; srcs[3] = sv.w;
        dsts[0] = dv.x; dsts[1] = dv.y; dsts[2] = dv.z; dsts[3] = dv.w;
#pragma unroll
        for (int k = 0; k < 4; ++k) {
            int pos = atomicAdd(&cursorp[dsts[k] << PADSH], 1);
            colv[pos] = srcs[k];
        }
    } else {
#pragma unroll
        for (int k = 0; k < 4; ++k) {
            int e = e0 + k;
            if (e < TOT_E) {
                int srcv, dstv;
                if (e < N_EDGES) { srcv = ei[e]; dstv = ei[N_EDGES + e]; }
                else             { srcv = dstv = e - N_EDGES; }
                int pos = atomicAdd(&cursorp[dstv << PADSH], 1);
                colv[pos] = srcv;
            }
        }
    }
}

// ---------------- layer-0 aggregation over x (dual-head, 256B/edge) ----------

__global__ __launch_bounds__(256) void agg0x_k(const unsigned short* __restrict__ xb,
                      const float* __restrict__ a_s, const float* __restrict__ a_d,
                      const int* __restrict__ start, const int* __restrict__ deg,
                      const int* __restrict__ colv,
                      unsigned short* __restrict__ xagg) {
    __shared__ float lexp[4][MAXD][2];
    const int lane = threadIdx.x & 63;
    const int wslot = threadIdx.x >> 6;
    const int node = blockIdx.x * 4 + wslot;
    if (node >= N_NODES) return;
    const int beg = start[node];
    const int degv = deg[node];
    const float ad0 = a_d[node * 2], ad1 = a_d[node * 2 + 1];
    const int* __restrict__ col = colv + beg;

    if (degv <= MAXD) {
        // ---- pass A: gather a_s, exp (max-free), stash to LDS, sum ----
        float s0 = 0.f, s1 = 0.f;
        for (int j = lane; j < degv; j += 64) {
            int s = col[j];
            float2 av = *reinterpret_cast<const float2*>(a_s + s * 2);
            float e0 = __expf(lrelu(av.x + ad0));
            float e1 = __expf(lrelu(av.y + ad1));
            *reinterpret_cast<float2*>(&lexp[wslot][j][0]) = make_float2(e0, e1);
            s0 += e0;
            s1 += e1;
        }
#pragma unroll
        for (int off = 32; off; off >>= 1) {
            s0 += __shfl_xor(s0, off);
            s1 += __shfl_xor(s1, off);
        }
        const float inv0 = 1.f / (s0 + 1e-16f);
        const float inv1 = 1.f / (s1 + 1e-16f);

        // ---- pass B: 4 edges/iter; quarter q owns edge 4i+q; lane covers
        // 8 x-channels [lq*8, lq*8+8); dual (e0,e1)-weighted accumulate ----
        const int q = lane >> 4;
        const int lq = lane & 15;
        const unsigned short* __restrict__ xp = xb + lq * 8;
        f32x2 aA[4] = {};   // e0-weighted
        f32x2 aB[4] = {};   // e1-weighted
        const int full = degv >> 2;
        for (int i = 0; i < full; ++i) {
            const int j = 4 * i + q;
            const int s = col[j];
            float2 ee = *reinterpret_cast<float2*>(&lexp[wslot][j][0]);
            const uint4 hv = *reinterpret_cast<const uint4*>(xp + (size_t)s * 128);
            const f32x2 al0 = {ee.x, ee.x};
            const f32x2 al1 = {ee.y, ee.y};
            f32x2 p;
            p.x = bf2f_lo(hv.x); p.y = bf2f_hi(hv.x);
            aA[0] = __builtin_elementwise_fma(p, al0, aA[0]);
            aB[0] = __builtin_elementwise_fma(p, al1, aB[0]);
            p.x = bf2f_lo(hv.y); p.y = bf2f_hi(hv.y);
            aA[1] = __builtin_elementwise_fma(p, al0, aA[1]);
            aB[1] = __builtin_elementwise_fma(p, al1, aB[1]);
            p.x = bf2f_lo(hv.z); p.y = bf2f_hi(hv.z);
            aA[2] = __builtin_elementwise_fma(p, al0, aA[2]);
            aB[2] = __builtin_elementwise_fma(p, al1, aB[2]);
            p.x = bf2f_lo(hv.w); p.y = bf2f_hi(hv.w);
            aA[3] = __builtin_elementwise_fma(p, al0, aA[3]);
            aB[3] = __builtin_elementwise_fma(p, al1, aB[3]);
        }
        {   // tail (degv & 3 edges)
            const int j = full * 4 + q;
            if (j < degv) {
                const int s = col[j];
                float2 ee = *reinterpret_cast<float2*>(&lexp[wslot][j][0]);
                const uint4 hv = *reinterpret_cast<const uint4*>(xp + (size_t)s * 128);
                const f32x2 al0 = {ee.x, ee.x};
                const f32x2 al1 = {ee.y, ee.y};
                f32x2 p;
                p.x = bf2f_lo(hv.x); p.y = bf2f_hi(hv.x);
                aA[0] = __builtin_elementwise_fma(p, al0, aA[0]);
                aB[0] = __builtin_elementwise_fma(p, al1, aB[0]);
                p.x = bf2f_lo(hv.y); p.y = bf2f_hi(hv.y);
                aA[1] = __builtin_elementwise_fma(p, al0, aA[1]);
                aB[1] = __builtin_elementwise_fma(p, al1, aB[1]);
                p.x = bf2f_lo(hv.z); p.y = bf2f_hi(hv.z);
                aA[2] = __builtin_elementwise_fma(p, al0, aA[2]);
                aB[2] = __builtin_elementwise_fma(p, al1, aB[2]);
                p.x = bf2f_lo(hv.w); p.y = bf2f_hi(hv.w);
                aA[3] = __builtin_elementwise_fma(p, al0, aA[3]);
                aB[3] = __builtin_elementwise_fma(p, al1, aB[3]);
            }
        }
        float acc[16];
#pragma unroll
        for (int c = 0; c < 4; ++c) {
            acc[2 * c]     = aA[c].x;
            acc[2 * c + 1] = aA[c].y;
            acc[8 + 2 * c]     = aB[c].x;
            acc[8 + 2 * c + 1] = aB[c].y;
        }
#pragma unroll
        for (int c = 0; c < 16; ++c) {
            acc[c] += __shfl_xor(acc[c], 16);
            acc[c] += __shfl_xor(acc[c], 32);
        }
        if (lane < 16) {
#pragma unroll
            for (int c = 0; c < 8; ++c)  acc[c] *= inv0;
#pragma unroll
            for (int c = 8; c < 16; ++c) acc[c] *= inv1;
            uint4 v0, v1;
            v0.x = f2bf_pack(acc[0], acc[1]);
            v0.y = f2bf_pack(acc[2], acc[3]);
            v0.z = f2bf_pack(acc[4], acc[5]);
            v0.w = f2bf_pack(acc[6], acc[7]);
            v1.x = f2bf_pack(acc[8], acc[9]);
            v1.y = f2bf_pack(acc[10], acc[11]);
            v1.z = f2bf_pack(acc[12], acc[13]);
            v1.w = f2bf_pack(acc[14], acc[15]);
            *reinterpret_cast<uint4*>(xagg + (size_t)node * 256 + lq * 8) = v0;
            *reinterpret_cast<uint4*>(xagg + (size_t)node * 256 + 128 + lq * 8) = v1;
        }
    } else {
        // ---- fallback: 3-pass max-subtracted; lane covers 2 x-channels ----
        const int end = beg + degv;
        float m0 = -INFINITY, m1 = -INFINITY;
        for (int e = beg + lane; e < end; e += 64) {
            int s = colv[e];
            m0 = fmaxf(m0, lrelu(a_s[s * 2] + ad0));
            m1 = fmaxf(m1, lrelu(a_s[s * 2 + 1] + ad1));
        }
#pragma unroll
        for (int off = 32; off; off >>= 1) {
            m0 = fmaxf(m0, __shfl_xor(m0, off));
            m1 = fmaxf(m1, __shfl_xor(m1, off));
        }
        float s0 = 0.f, s1 = 0.f;
        for (int e = beg + lane; e < end; e += 64) {
            int s = colv[e];
            s0 += __expf(lrelu(a_s[s * 2] + ad0) - m0);
            s1 += __expf(lrelu(a_s[s * 2 + 1] + ad1) - m1);
        }
#pragma unroll
        for (int off = 32; off; off >>= 1) {
            s0 += __shfl_xor(s0, off);
            s1 += __shfl_xor(s1, off);
        }
        float inv0 = 1.f / (s0 + 1e-16f);
        float inv1 = 1.f / (s1 + 1e-16f);
        const int cbase = lane * 2;
        float a00 = 0.f, a01 = 0.f, a10 = 0.f, a11 = 0.f;
        for (int e = beg; e < end; ++e) {
            int s = colv[e];
            float2 av = *reinterpret_cast<const float2*>(a_s + s * 2);
            float al0 = __expf(lrelu(av.x + ad0) - m0) * inv0;
            float al1 = __expf(lrelu(av.y + ad1) - m1) * inv1;
            unsigned int xv = *reinterpret_cast<const unsigned int*>(
                xb + (size_t)s * 128 + cbase);
            float x0 = bf2f_lo(xv), x1 = bf2f_hi(xv);
            a00 = fmaf(x0, al0, a00);
            a01 = fmaf(x1, al0, a01);
            a10 = fmaf(x0, al1, a10);
            a11 = fmaf(x1, al1, a11);
        }
        *reinterpret_cast<unsigned int*>(xagg + (size_t)node * 256 + cbase) =
            f2bf_pack(a00, a01);
        *reinterpret_cast<unsigned int*>(xagg + (size_t)node * 256 + 128 + cbase) =
            f2bf_pack(a10, a11);
    }
}

// ---------------- GEMM: hact = tanh(xagg_h @ W0 + b0) in-register, then this
// block's 64-col slice of the 8 projection dots -> part[cb][row][8].
// 64 rows x 64 cols per block (16 rows/wave, acc[1][4]); grid 3128.
// Plain stores (single writer per (cb,row)); reduce_part_k sums the 4 slices.

__global__ __launch_bounds__(256) void gemm_tanh_k(
        const unsigned short* __restrict__ A,   // xagg [M][256] bf16
        const unsigned short* __restrict__ BT,  // WT0 [256][128] bf16
        const float* __restrict__ b0,
        const float* __restrict__ pv,           // [256][8] fp32
        float* __restrict__ part, int M) {
    const int bid = blockIdx.x;
    const int cb = bid & 3;              // col-block: cols [cb*64, cb*64+64)
    const int gy = bid >> 2;
    const int head = cb >> 1;
    const int lane = threadIdx.x & 63;
    const int wv = threadIdx.x >> 6;
    const int lm = lane & 15;
    const int g8 = (lane >> 4) * 8;
    const int row0 = gy * 64 + wv * 16;
    const int n0 = cb * 64;

    int ra0 = row0 + lm;
    if (ra0 >= M) ra0 = M - 1;
    const unsigned short* pa0 = A + (size_t)ra0 * 256 + head * 128 + g8;
    const unsigned short* pb  = BT + (size_t)(n0 + lm) * 128 + g8;

    f32x4 acc[4] = {};
#pragma unroll
    for (int kt = 0; kt < 128; kt += 32) {
        bf16x8 a0 = *reinterpret_cast<const bf16x8*>(pa0 + kt);
        bf16x8 b0f = *reinterpret_cast<const bf16x8*>(pb + kt);
        bf16x8 b1f = *reinterpret_cast<const bf16x8*>(pb + 16 * 128 + kt);
        bf16x8 b2f = *reinterpret_cast<const bf16x8*>(pb + 32 * 128 + kt);
        bf16x8 b3f = *reinterpret_cast<const bf16x8*>(pb + 48 * 128 + kt);
        acc[0] = __builtin_amdgcn_mfma_f32_16x16x32_bf16(a0, b0f, acc[0], 0, 0, 0);
        acc[1] = __builtin_amdgcn_mfma_f32_16x16x32_bf16(a0, b1f, acc[1], 0, 0, 0);
        acc[2] = __builtin_amdgcn_mfma_f32_16x16x32_bf16(a0, b2f, acc[2], 0, 0, 0);
        acc[3] = __builtin_amdgcn_mfma_f32_16x16x32_bf16(a0, b3f, acc[3], 0, 0, 0);
    }

    // per-column constants for my 4 col-frags
    float bc[4];
    float4 pA[4], pB[4];
#pragma unroll
    for (int j = 0; j < 4; ++j) {
        int c = n0 + j * 16 + lm;
        bc[j] = b0[c];
        pA[j] = *reinterpret_cast<const float4*>(pv + (size_t)c * 8);
        pB[j] = *reinterpret_cast<const float4*>(pv + (size_t)c * 8 + 4);
    }

    float pr[8][4];
#pragma unroll
    for (int p = 0; p < 8; ++p)
#pragma unroll
        for (int r = 0; r < 4; ++r) pr[p][r] = 0.f;
#pragma unroll
    for (int j = 0; j < 4; ++j)
#pragma unroll
        for (int r = 0; r < 4; ++r) {
            float th = tanhf(acc[j][r] + bc[j]);
            pr[0][r] = fmaf(th, pA[j].x, pr[0][r]);
            pr[1][r] = fmaf(th, pA[j].y, pr[1][r]);
            pr[2][r] = fmaf(th, pA[j].z, pr[2][r]);
            pr[3][r] = fmaf(th, pA[j].w, pr[3][r]);
            pr[4][r] = fmaf(th, pB[j].x, pr[4][r]);
            pr[5][r] = fmaf(th, pB[j].y, pr[5][r]);
            pr[6][r] = fmaf(th, pB[j].z, pr[6][r]);
            pr[7][r] = fmaf(th, pB[j].w, pr[7][r]);
        }
#pragma unroll
    for (int off = 1; off < 16; off <<= 1)
#pragma unroll
        for (int p = 0; p < 8; ++p)
#pragma unroll
            for (int r = 0; r < 4; ++r)
                pr[p][r] += __shfl_xor(pr[p][r], off);
    if (lm == 0) {
        int rb = row0 + (lane >> 4) * 4;
#pragma unroll
        for (int r = 0; r < 4; ++r) {
            if (rb + r < M) {
                float4* dst = reinterpret_cast<float4*>(
                    part + ((size_t)cb * N_NODES + rb + r) * 8);
                dst[0] = make_float4(pr[0][r], pr[1][r], pr[2][r], pr[3][r]);
                dst[1] = make_float4(pr[4][r], pr[5][r], pr[6][r], pr[7][r]);
            }
        }
    }
}

// ---------------- sum the 4 col-block partials -> asd1[n][8] ----------------

__global__ void reduce_part_k(const float* __restrict__ part,
                              float* __restrict__ asd1) {
    int i = blockIdx.x * blockDim.x + threadIdx.x;
    if (i < N_NODES * 8) {
        const size_t S = (size_t)N_NODES * 8;
        asd1[i] = part[i] + part[i + S] + part[i + 2 * S] + part[i + 3 * S];
    }
}

// ---------------- layer-1 aggregation + final linear + softmax ----------------
// asd1[n][8] = (as1_0, as1_1, ad1_0, ad1_1, g00, g01, g10, g11)

__global__ __launch_bounds__(256) void agg_final_k(
        const float* __restrict__ asd1, const int* __restrict__ start,
        const int* __restrict__ deg, const int* __restrict__ colv,
        const float* __restrict__ c2, float* __restrict__ out) {
    const int lane = threadIdx.x & 63;
    const int node = blockIdx.x * 4 + (threadIdx.x >> 6);
    if (node >= N_NODES) return;
    const int beg = start[node];
    const int degv = deg[node];
    const float ad0 = asd1[node * 8 + 2];
    const float ad1v = asd1[node * 8 + 3];
    const int* __restrict__ col = colv + beg;

    float s0 = 0.f, s1 = 0.f, A00 = 0.f, A01 = 0.f, A10 = 0.f, A11 = 0.f;
    for (int j = lane; j < degv; j += 64) {
        int s = col[j];
        const float* rs = asd1 + (size_t)s * 8;
        float2 av = *reinterpret_cast<const float2*>(rs);
        float4 gv = *reinterpret_cast<const float4*>(rs + 4);
        float e0 = __expf(lrelu(av.x + ad0));
        float e1 = __expf(lrelu(av.y + ad1v));
        s0 += e0;
        s1 += e1;
        A00 = fmaf(e0, gv.x, A00);
        A01 = fmaf(e0, gv.y, A01);
        A10 = fmaf(e1, gv.z, A10);
        A11 = fmaf(e1, gv.w, A11);
    }
#pragma unroll
    for (int off = 32; off; off >>= 1) {
        s0  += __shfl_xor(s0, off);
        s1  += __shfl_xor(s1, off);
        A00 += __shfl_xor(A00, off);
        A01 += __shfl_xor(A01, off);
        A10 += __shfl_xor(A10, off);
        A11 += __shfl_xor(A11, off);
    }
    if (lane == 0) {
        float i0 = 1.f / (s0 + 1e-16f), i1 = 1.f / (s1 + 1e-16f);
        float z0 = A00 * i0 + A10 * i1 + c2[0];
        float z1 = A01 * i0 + A11 * i1 + c2[1];
        float mx = fmaxf(z0, z1);
        float e0 = __expf(z0 - mx), e1 = __expf(z1 - mx);
        float inv = 1.f / (e0 + e1);
        out[node * 2 + 0] = e0 * inv;
        out[node * 2 + 1] = e1 * inv;
    }
}

// ---------------- launch ----------------

extern "C" void kernel_launch(void* const* d_in, const int* in_sizes, int n_in,
                              void* d_out, int out_size, void* d_ws, size_t ws_size,
                              hipStream_t stream) {
    const float* x        = (const float*)d_in[0];
    const int*   ei       = (const int*)d_in[1];
    const float* W0       = (const float*)d_in[2];
    const float* att_src0 = (const float*)d_in[3];
    const float* att_dst0 = (const float*)d_in[4];
    const float* b0       = (const float*)d_in[5];
    const float* W1       = (const float*)d_in[6];
    const float* att_src1 = (const float*)d_in[7];
    const float* att_dst1 = (const float*)d_in[8];
    const float* b1       = (const float*)d_in[9];
    const float* Wl       = (const float*)d_in[10];
    const float* bl       = (const float*)d_in[11];
    float* out = (float*)d_out;

    // workspace layout
    unsigned short* xb   = (unsigned short*)d_ws;                 // N*128 bf16
    unsigned short* xagg = xb + (size_t)N_NODES * 128;            // N*256 bf16
    unsigned short* WT0  = xagg + (size_t)N_NODES * 256;          // 256*128 bf16
    float* w0buf = (float*)(WT0 + 256 * 128);                     // 128*4 f32
    float* pv    = w0buf + 128 * 4;                               // 256*8 f32
    float* as0   = pv + 256 * 8;                                  // N*2
    float* ad0   = as0 + N_NODES * 2;                             // N*2
    float* asd1  = ad0 + N_NODES * 2;                             // N*8
    float* part  = asd1 + (size_t)N_NODES * 8;                    // 4*N*8
    int*   degp  = (int*)(part + (size_t)N_NODES * 32);           // N*32 (padded)
    int* cursorp = degp + (size_t)N_NODES * 32;                   // N*32 (padded)
    int* deg     = cursorp + (size_t)N_NODES * 32;                // N
    int* start   = deg + N_NODES;                                 // N
    int* total   = start + N_NODES;                               // 1
    float* c2    = (float*)(total + 1);                           // 2
    int* colv    = (int*)(c2 + 2);                                // E + N

    // ---- zero + pushdown-vector precompute ----
    zero_pre_k<<<(N_NODES * 32 / 4 + 255) / 256, 256, 0, stream>>>(
        (uint4*)degp, total, c2, W0, att_src0, att_dst0,
        W1, att_src1, att_dst1, Wl, w0buf, pv);

    // ---- fused prep ----
    prep_k<<<PREP_BLKS, 256, 0, stream>>>(x, xb, W0, WT0, ei, degp,
                                          w0buf, as0, ad0, Wl, b1, bl, c2);

    // ---- CSR offsets + scatter (4 edges/thread) ----
    offsets_k<<<(N_NODES + 255) / 256, 256, 0, stream>>>(degp, start, deg, cursorp, total);
    scatter_k<<<(TOT_E + 1023) / 1024, 256, 0, stream>>>(ei, cursorp, colv);

    int nn4 = (N_NODES + 3) / 4;

    // ---- layer 0: aggregate x (dual-head), then GEMM+tanh+projections ----
    agg0x_k<<<nn4, 256, 0, stream>>>(xb, as0, ad0, start, deg, colv, xagg);
    gemm_tanh_k<<<GT_BLKS, 256, 0, stream>>>(xagg, WT0, b0, pv, part, N_NODES);
    reduce_part_k<<<(N_NODES * 8 + 255) / 256, 256, 0, stream>>>(part, asd1);

    // ---- layer 1 aggregation + final linear + softmax ----
    agg_final_k<<<nn4, 256, 0, stream>>>(asd1, start, deg, colv, c2, out);
}